// Round 12
// baseline (322.195 us; speedup 1.0000x reference)
//
#include <hip/hip_runtime.h>
#include <hip/hip_bf16.h>

typedef __hip_bfloat16 bf16;
typedef float f32x4 __attribute__((ext_vector_type(4)));
typedef short s16x8 __attribute__((ext_vector_type(8)));

#define B_   16
#define CIN  256
#define CQK  32
#define CV   128
#define VDIM 64
#define TDIM 64
#define P    (VDIM * TDIM)   // 4096

static __device__ __forceinline__ ushort f2bf(float f) {
    bf16 h = __float2bfloat16(f);
    return *(ushort*)&h;
}
static __device__ __forceinline__ float bf2f(ushort u) {
    bf16 h = *(bf16*)&u;
    return __bfloat162float(h);
}

// async 16B-per-lane global -> LDS DMA (LDS dest = wave-uniform base + lane*16)
static __device__ __forceinline__ void gld16(const void* gsrc, void* ldst) {
    __builtin_amdgcn_global_load_lds(
        (const __attribute__((address_space(1))) void*)gsrc,
        (__attribute__((address_space(3))) void*)ldst,
        16, 0, 0);
}

#define MFMA16(A, B, C) __builtin_amdgcn_mfma_f32_16x16x32_bf16((A), (B), (C), 0, 0, 0)

// ---------------------------------------------------------------------------
// repack_w: weights -> [tap][oc][ci] bf16 (+ hi/lo split for q,k); zero zp page.
// ---------------------------------------------------------------------------
__global__ __launch_bounds__(256) void repack_w(
    const float* __restrict__ wq, const float* __restrict__ wk,
    const float* __restrict__ wv, const float* __restrict__ wo,
    ushort* __restrict__ wvT, ushort* __restrict__ woT,
    ushort* __restrict__ wqh, ushort* __restrict__ wql,
    ushort* __restrict__ zp)
{
    if (blockIdx.x == 0) ((uint*)zp)[threadIdx.x] = 0;   // 1KB zero page
    int i = blockIdx.x * 256 + threadIdx.x;
    const int NQK = 9 * 64 * 256;      // 147456
    const int NV  = 9 * 128 * 256;     // 294912
    if (i < NQK) {
        int tap = i / (64 * 256);
        int r   = i % (64 * 256);
        int oc  = r >> 8;
        int ci  = r & 255;
        const float* src = (oc < 32) ? wq : wk;
        float f = src[(size_t)(oc & 31) * 2304 + ci * 9 + tap];
        ushort h = f2bf(f);
        wqh[i] = h;
        wql[i] = f2bf(f - bf2f(h));
    } else if (i < NQK + NV) {
        i -= NQK;
        int tap = i / (128 * 256);
        int r   = i % (128 * 256);
        int oc  = r >> 8;
        int ci  = r & 255;
        wvT[i] = f2bf(wv[(size_t)oc * 2304 + ci * 9 + tap]);
    } else {
        i -= NQK + NV;
        int tap = i / (256 * 128);
        int r   = i % (256 * 128);
        int oc  = r >> 7;
        int ci  = r & 127;
        woT[i] = f2bf(wo[(size_t)oc * 1152 + ci * 9 + tap]);
    }
}

// ---------------------------------------------------------------------------
// repack_x2: x [B][256][64y][64t] f32 -> xh,xl [B][64t][64y][256ci] bf16
// ---------------------------------------------------------------------------
__global__ __launch_bounds__(256) void repack_x2(
    const float* __restrict__ x, ushort* __restrict__ xhd, ushort* __restrict__ xld)
{
    const int b = blockIdx.x >> 6;
    const int y = blockIdx.x & 63;
    __shared__ ushort th[64][257];
    __shared__ ushort tl_[64][257];
    const int t  = threadIdx.x & 63;
    const int cq = threadIdx.x >> 6;
    const float* xb = x + (((size_t)b * CIN) * VDIM + y) * TDIM;
    for (int ci = cq; ci < 256; ci += 4) {
        float f = xb[(size_t)ci * P + t];
        ushort h = f2bf(f);
        th[t][ci]  = h;
        tl_[t][ci] = f2bf(f - bf2f(h));
    }
    __syncthreads();
    const int ci4 = (threadIdx.x & 63) * 4;
    const int tr0 = threadIdx.x >> 6;
    for (int tr = tr0; tr < 64; tr += 4) {
        ushort4 uh, ul;
        uh.x = th[tr][ci4];     uh.y = th[tr][ci4 + 1];
        uh.z = th[tr][ci4 + 2]; uh.w = th[tr][ci4 + 3];
        ul.x = tl_[tr][ci4];     ul.y = tl_[tr][ci4 + 1];
        ul.z = tl_[tr][ci4 + 2]; ul.w = tl_[tr][ci4 + 3];
        const size_t o = ((((size_t)b * 64 + tr) * 64 + y) * 256 + ci4);
        *(ushort4*)(xhd + o) = uh;
        *(ushort4*)(xld + o) = ul;
    }
}

// ---------------------------------------------------------------------------
// Stage one 64-ci chunk tile [3 dx][66 yl][64 ci] (rows of 128B) into smem[0..25344).
// 25 gld16 rounds (1KB = 8 rows each), split 7/6/6/6 across waves.
// Swizzle folded into SOURCE channel: ci slot = (lane&7) ^ (row&7).
// R9 ordering preserved: stage issued immediately before the drain barrier.
// ---------------------------------------------------------------------------
#define STAGE64(SRC, CIB)                                                         \
    {                                                                             \
        const int r0 = (w == 0) ? 0 : (7 + (w - 1) * 6);                          \
        const int nr = (w == 0) ? 7 : 6;                                          \
        for (int j = 0; j < nr; ++j) {                                            \
            const int ii  = r0 + j;                                              \
            const int row = ii * 8 + (lane >> 3);                                 \
            const int dxs = (row * 993) >> 16;                                    \
            const int yl  = row - dxs * 66;                                       \
            const int tp  = t0 + dxs - 1;                                         \
            const int yp  = yl - 1;                                               \
            const int cis = (lane & 7) ^ (row & 7);                               \
            const bool ok = ((unsigned)tp < 64u) && ((unsigned)yp < 64u) && (row < 198); \
            const ushort* sp = ok                                                 \
                ? (SRC) + ((((size_t)b * 64 + tp) * 64 + yp) * 256 + (CIB) + cis * 8) \
                : zp + (size_t)lane * 8;                                          \
            gld16(sp, smem + ii * 1024);                                          \
        }                                                                         \
    }

// Read the 4 B-fragments for tap (dy,dxp) at local k-step KK (0/1).
#define READ_BFR64(BFR, DY, DXP, KK)                                              \
    {                                                                             \
        _Pragma("unroll")                                                         \
        for (int nf = 0; nf < 4; ++nf) {                                          \
            const int ylr = nf * 16 + (lane & 15) + (DY);                         \
            const int row = (DXP) * 66 + ylr;                                     \
            BFR[nf] = *(const s16x8*)(smem + row * 128 +                          \
                       ((((KK) * 64 + (lane >> 4) * 16)) ^ ((row & 7) << 4)));    \
        }                                                                         \
    }

// ---------------------------------------------------------------------------
// qkvattn: fused q/k/v conv (MFMA implicit GEMM) + MFMA attention per (b,t0).
// LDS DIET (R12): conv chunks 64-ci (25.3KB buffer, 8 stages); tail compressed
// to 32KB via overlays (P over dead q/k, avL over dead vsT, with barriers
// after the respective register preloads). Block LDS 32768 -> 4 blocks/CU
// resident (16 waves) vs 51.2KB/3-resident before. Arithmetic is bitwise
// identical to R9/R11 (same MFMA order, same ops).
// ---------------------------------------------------------------------------
__global__ __launch_bounds__(256) void qkvattn(
    const ushort* __restrict__ xh, const ushort* __restrict__ xl,
    const ushort* __restrict__ wvT,
    const ushort* __restrict__ wqh, const ushort* __restrict__ wql,
    const ushort* __restrict__ zp,
    float* __restrict__ attn_out, ushort* __restrict__ av)
{
    // XCD-bijective swizzle (1024 blocks, 8 XCDs, 128/XCD)
    const int bid  = ((blockIdx.x & 7) << 7) | (blockIdx.x >> 3);
    const int b    = bid >> 6;
    const int t0   = bid & 63;
    const int tid  = threadIdx.x;
    const int lane = tid & 63;
    const int w    = tid >> 6;

    __shared__ __align__(16) char smem[32768];

    f32x4 accv[2][4];
    f32x4 accq[4];
#pragma unroll
    for (int m = 0; m < 2; ++m)
#pragma unroll
        for (int nf = 0; nf < 4; ++nf) accv[m][nf] = (f32x4){0.f, 0.f, 0.f, 0.f};
#pragma unroll
    for (int nf = 0; nf < 4; ++nf) accq[nf] = (f32x4){0.f, 0.f, 0.f, 0.f};

    const int ocv  = w * 32 + (lane & 15);        // v channel base (m adds 16)
    const int ocqk = w * 16 + (lane & 15);        // combined q|k channel
    const int ko8  = (lane >> 4) * 8;

#define WV_(TAP, M, KK) (const s16x8*)(wvT + (size_t)((TAP) * 128 + ocv + (M) * 16) * 256 + cib + (KK) * 32 + ko8)
#define WQ_(ARR, TAP, KK) (const s16x8*)((ARR) + (size_t)((TAP) * 64 + ocqk) * 256 + cib + (KK) * 32 + ko8)

#pragma unroll 1
    for (int cc = 0; cc < 4; ++cc) {
        const int cib = cc * 64;

        __syncthreads();              // protect smem from prior readers
        STAGE64(xh, cib)
        __syncthreads();              // drains vmcnt -> DMAs complete

        // ---- merged v + qk-hi pass over x_hi (shared bfr reads) ----
#pragma unroll 1
        for (int tap = 0; tap < 9; ++tap) {
            const int dy = tap / 3, dxp = tap % 3;
            s16x8 va[2], vb[2], ha[2], la[2];
#pragma unroll
            for (int kk = 0; kk < 2; ++kk) {
                va[kk] = *WV_(tap, 0, kk);
                vb[kk] = *WV_(tap, 1, kk);
                ha[kk] = *WQ_(wqh, tap, kk);
                la[kk] = *WQ_(wql, tap, kk);
            }
#pragma unroll
            for (int kk = 0; kk < 2; ++kk) {
                s16x8 bfr[4];
                READ_BFR64(bfr, dy, dxp, kk)
#pragma unroll
                for (int nf = 0; nf < 4; ++nf)
                    accv[0][nf] = MFMA16(va[kk], bfr[nf], accv[0][nf]);
#pragma unroll
                for (int nf = 0; nf < 4; ++nf)
                    accv[1][nf] = MFMA16(vb[kk], bfr[nf], accv[1][nf]);
#pragma unroll
                for (int nf = 0; nf < 4; ++nf)
                    accq[nf] = MFMA16(ha[kk], bfr[nf], accq[nf]);
#pragma unroll
                for (int nf = 0; nf < 4; ++nf)
                    accq[nf] = MFMA16(la[kk], bfr[nf], accq[nf]);
            }
        }

        __syncthreads();              // all reads of x_hi tile done
        STAGE64(xl, cib)
        __syncthreads();

        // ---- qk lo pass (w_hi . x_lo) ----
#pragma unroll 1
        for (int tap = 0; tap < 9; ++tap) {
            const int dy = tap / 3, dxp = tap % 3;
            s16x8 ha[2];
#pragma unroll
            for (int kk = 0; kk < 2; ++kk) ha[kk] = *WQ_(wqh, tap, kk);
#pragma unroll
            for (int kk = 0; kk < 2; ++kk) {
                s16x8 bfr[4];
                READ_BFR64(bfr, dy, dxp, kk)
#pragma unroll
                for (int nf = 0; nf < 4; ++nf)
                    accq[nf] = MFMA16(ha[kk], bfr[nf], accq[nf]);
            }
        }
    }
#undef WV_
#undef WQ_
    __syncthreads();   // conv scratch dead; repurpose LDS for MFMA attention

    const int l15 = lane & 15, lg = lane >> 4;

    // ---- phase A: conv accumulators -> LDS (q@0 / k@8192 bf16 hi|lo, vsT@16384) ----
    {
        char* qkb = smem + ((w < 2) ? 0 : 8192);
        const int c0 = (w & 1) * 16 + lg * 4;
#pragma unroll
        for (int nf = 0; nf < 4; ++nf) {
            const int y = nf * 16 + l15;
            ushort4 h4, l4;
#pragma unroll
            for (int r = 0; r < 4; ++r) {
                ushort h = f2bf(accq[nf][r]);
                ((ushort*)&h4)[r] = h;
                ((ushort*)&l4)[r] = f2bf(accq[nf][r] - bf2f(h));
            }
            const int swz = (y & 7) << 4;
            *(ushort4*)(qkb + y * 128 + ((2 * c0) ^ swz))      = h4;
            *(ushort4*)(qkb + y * 128 + ((64 + 2 * c0) ^ swz)) = l4;
        }
        // vsT[c][j] = v[j][c] (bf16), swizzled rows
#pragma unroll
        for (int m = 0; m < 2; ++m)
#pragma unroll
            for (int nf = 0; nf < 4; ++nf) {
                const int y = nf * 16 + l15;
#pragma unroll
                for (int r = 0; r < 4; ++r) {
                    const int oc = w * 32 + m * 16 + lg * 4 + r;
                    *(ushort*)(smem + 16384 + oc * 128 + ((2 * y) ^ ((oc & 7) << 4)))
                        = f2bf(accv[m][nf][r]);
                }
            }
    }
    __syncthreads();

    // ---- phase B: S via MFMA (3-pass), softmax in-register; P overlays q/k ----
    f32x4 pv[4];
    {
        const int yq = w * 16 + l15;
        const int sq = (yq & 7) << 4;
        s16x8 qh = *(const s16x8*)(smem + yq * 128 + ((lg * 16) ^ sq));
        s16x8 ql = *(const s16x8*)(smem + yq * 128 + ((64 + lg * 16) ^ sq));
        s16x8 kh[4], kl[4];
#pragma unroll
        for (int jt = 0; jt < 4; ++jt) {
            const int jr = jt * 16 + l15;
            const int sk = (jr & 7) << 4;
            kh[jt] = *(const s16x8*)(smem + 8192 + jr * 128 + ((lg * 16) ^ sk));
            kl[jt] = *(const s16x8*)(smem + 8192 + jr * 128 + ((64 + lg * 16) ^ sk));
        }
        __syncthreads();   // ALL q/k reads complete -> safe to overlay P

        f32x4 sAcc[4];
#pragma unroll
        for (int jt = 0; jt < 4; ++jt) {
            f32x4 a = (f32x4){0.f, 0.f, 0.f, 0.f};
            a = MFMA16(qh, kh[jt], a);
            a = MFMA16(qh, kl[jt], a);
            a = MFMA16(ql, kh[jt], a);
            sAcc[jt] = a;   // S[w*16 + lg*4 + r][jt*16 + l15]
        }
        // softmax over j: in-register + 16-lane shfl_xor
        float mx[4], sum[4];
#pragma unroll
        for (int r = 0; r < 4; ++r)
            mx[r] = fmaxf(fmaxf(sAcc[0][r], sAcc[1][r]), fmaxf(sAcc[2][r], sAcc[3][r]));
#pragma unroll
        for (int d = 1; d < 16; d <<= 1)
#pragma unroll
            for (int r = 0; r < 4; ++r) mx[r] = fmaxf(mx[r], __shfl_xor(mx[r], d));
#pragma unroll
        for (int r = 0; r < 4; ++r) sum[r] = 0.f;
#pragma unroll
        for (int jt = 0; jt < 4; ++jt)
#pragma unroll
            for (int r = 0; r < 4; ++r) {
                pv[jt][r] = expf(sAcc[jt][r] - mx[r]);
                sum[r] += pv[jt][r];
            }
#pragma unroll
        for (int d = 1; d < 16; d <<= 1)
#pragma unroll
            for (int r = 0; r < 4; ++r) sum[r] += __shfl_xor(sum[r], d);
#pragma unroll
        for (int r = 0; r < 4; ++r) sum[r] = 1.f / sum[r];
#pragma unroll
        for (int jt = 0; jt < 4; ++jt)
#pragma unroll
            for (int r = 0; r < 4; ++r) pv[jt][r] *= sum[r];

        // attn write (fp32)
        float* ao = attn_out + (size_t)bid * 4096;
#pragma unroll
        for (int jt = 0; jt < 4; ++jt)
#pragma unroll
            for (int r = 0; r < 4; ++r)
                ao[(w * 16 + lg * 4 + r) * 64 + jt * 16 + l15] = pv[jt][r];

        // P -> bf16 hi@0 / lo@8192 (over dead q/k), swizzled rows
#pragma unroll
        for (int jt = 0; jt < 4; ++jt)
#pragma unroll
            for (int r = 0; r < 4; ++r) {
                const int i = w * 16 + lg * 4 + r;
                const int j = jt * 16 + l15;
                const int off = i * 128 + ((2 * j) ^ ((i & 7) << 4));
                ushort h = f2bf(pv[jt][r]);
                *(ushort*)(smem + off)        = h;
                *(ushort*)(smem + 8192 + off) = f2bf(pv[jt][r] - bf2f(h));
            }
    }
    __syncthreads();

    // ---- phase C: AV^T = V^T (Phi + Plo) via MFMA; avL overlays vsT ----
    {
        s16x8 vt[2][2];
#pragma unroll
        for (int c2 = 0; c2 < 2; ++c2)
#pragma unroll
            for (int ks = 0; ks < 2; ++ks) {
                const int c = (w * 2 + c2) * 16 + l15;
                vt[c2][ks] = *(const s16x8*)(smem + 16384 + c * 128 +
                                             ((ks * 64 + lg * 16) ^ ((c & 7) << 4)));
            }
        __syncthreads();   // ALL vsT reads complete -> safe to overlay avL

        f32x4 acc2[2][4];
#pragma unroll
        for (int c2 = 0; c2 < 2; ++c2)
#pragma unroll
            for (int it = 0; it < 4; ++it) acc2[c2][it] = (f32x4){0.f, 0.f, 0.f, 0.f};

#pragma unroll
        for (int it = 0; it < 4; ++it) {
            const int i = it * 16 + l15;
            const int si = (i & 7) << 4;
            s16x8 ph[2], pl[2];
#pragma unroll
            for (int ks = 0; ks < 2; ++ks) {
                ph[ks] = *(const s16x8*)(smem + i * 128 + ((ks * 64 + lg * 16) ^ si));
                pl[ks] = *(const s16x8*)(smem + 8192 + i * 128 + ((ks * 64 + lg * 16) ^ si));
            }
#pragma unroll
            for (int c2 = 0; c2 < 2; ++c2)
#pragma unroll
                for (int ks = 0; ks < 2; ++ks) {
                    acc2[c2][it] = MFMA16(vt[c2][ks], ph[ks], acc2[c2][it]);
                    acc2[c2][it] = MFMA16(vt[c2][ks], pl[ks], acc2[c2][it]);
                }
        }
        // avL[i][c] (bf16) swizzled [64][256B] rows at bytes [16384, 32768)
#pragma unroll
        for (int c2 = 0; c2 < 2; ++c2)
#pragma unroll
            for (int it = 0; it < 4; ++it)
#pragma unroll
                for (int r = 0; r < 4; ++r) {
                    const int c = (w * 2 + c2) * 16 + lg * 4 + r;
                    const int i = it * 16 + l15;
                    *(ushort*)(smem + 16384 + i * 256 + ((2 * c) ^ ((i & 7) << 4)))
                        = f2bf(acc2[c2][it][r]);
                }
    }
    __syncthreads();

    // ---- phase D: avL -> global, fully coalesced ----
    {
        uint* avg = (uint*)(av + (size_t)bid * 8192);
#pragma unroll
        for (int t = 0; t < 16; ++t) {
            const int idx = t * 256 + tid;
            const int i  = idx >> 6;
            const int cc = idx & 63;
            avg[idx] = *(const uint*)(smem + 16384 + i * 256 + ((4 * cc) ^ ((i & 7) << 4)));
        }
    }
}

// ---------------------------------------------------------------------------
// out_conv_mfma: 512-thread / 8-wave block = (b,y): M=256 oc, N=64 t,
// K=128ci*9tap. av-halo tile staged ONCE per (b,y). (R11, unchanged)
// ---------------------------------------------------------------------------
__global__ __launch_bounds__(512) void out_conv_mfma(
    const float* __restrict__ x,
    const ushort* __restrict__ av,
    const ushort* __restrict__ woT,
    const ushort* __restrict__ zp,
    const float* __restrict__ sigma,
    float* __restrict__ out)
{
    // XCD-bijective swizzle (1024 blocks, 128/XCD)
    const int bid  = ((blockIdx.x & 7) << 7) | (blockIdx.x >> 3);
    const int y    = bid & 63;
    const int b    = bid >> 6;
    const int tid  = threadIdx.x;
    const int lane = tid & 63;
    const int w    = tid >> 6;           // 0..7

    __shared__ __align__(16) char smem[51200];
    char* btile = smem;

    f32x4 acc[2][4];
#pragma unroll
    for (int m = 0; m < 2; ++m)
#pragma unroll
        for (int nf = 0; nf < 4; ++nf) acc[m][nf] = (f32x4){0.f, 0.f, 0.f, 0.f};

    // stage [3 dy][66 tl][128 ci] from av via gload_lds (swizzle in source);
    // 50 DMA rows split 7/7/6/6/6/6/6/6 across 8 waves.
    {
        const int i0 = (w < 2) ? w * 7 : 14 + (w - 2) * 6;
        const int ni = (w < 2) ? 7 : 6;
        for (int j = 0; j < ni; ++j) {
            const int ii  = i0 + j;
            const int row = ii * 4 + (lane >> 4);
            const int dys = (row * 993) >> 16;
            const int tl  = row - dys * 66;
            const int yp  = y + dys - 1;
            const int tp  = tl - 1;
            const int chg = (lane & 15) ^ (row & 7);
            const bool ok = ((unsigned)yp < 64u) && ((unsigned)tp < 64u) && (row < 198);
            const ushort* sp = ok
                ? av + ((((size_t)b * 64 + tp) * 64 + yp) * 128 + chg * 8)
                : zp + (size_t)lane * 8;
            gld16(sp, btile + ii * 1024);
        }
    }
    __syncthreads();

    const int oc  = w * 32 + (lane & 15);
    const int ko8 = (lane >> 4) * 8;
#define WOO(TAP, M, KK) (const s16x8*)(woT + (size_t)((TAP) * 256 + oc + (M) * 16) * 128 + (KK) * 32 + ko8)
#pragma unroll 1
    for (int tap = 0; tap < 9; ++tap) {
        const int dy = tap / 3, dxp = tap % 3;
        s16x8 wa[4], wb[4];
#pragma unroll
        for (int kk = 0; kk < 4; ++kk) {
            wa[kk] = *WOO(tap, 0, kk);
            wb[kk] = *WOO(tap, 1, kk);
        }
#pragma unroll
        for (int kk = 0; kk < 4; ++kk) {
            s16x8 bfr[4];
#pragma unroll
            for (int nf = 0; nf < 4; ++nf) {
                const int tl = nf * 16 + (lane & 15) + dxp;
                const int row = dy * 66 + tl;
                const int bir = kk * 64 + (lane >> 4) * 16;
                bfr[nf] = *(const s16x8*)(btile + row * 256 + (bir ^ ((row & 7) << 4)));
            }
#pragma unroll
            for (int nf = 0; nf < 4; ++nf)
                acc[0][nf] = MFMA16(wa[kk], bfr[nf], acc[0][nf]);
#pragma unroll
            for (int nf = 0; nf < 4; ++nf)
                acc[1][nf] = MFMA16(wb[kk], bfr[nf], acc[1][nf]);
        }
    }
#undef WOO

    const float s = sigma[0];
#pragma unroll
    for (int m = 0; m < 2; ++m)
#pragma unroll
        for (int nf = 0; nf < 4; ++nf)
#pragma unroll
            for (int r = 0; r < 4; ++r) {
                const int occ = w * 32 + m * 16 + (lane >> 4) * 4 + r;
                const int t   = nf * 16 + (lane & 15);
                const size_t a = (((size_t)b * 256 + occ) * 64 + y) * 64 + t;
                out[a] = x[a] + s * acc[m][nf][r];
            }
}

// ---------------------------------------------------------------------------
extern "C" void kernel_launch(void* const* d_in, const int* in_sizes, int n_in,
                              void* d_out, int out_size, void* d_ws, size_t ws_size,
                              hipStream_t stream)
{
    const float* x     = (const float*)d_in[0];
    const float* wq    = (const float*)d_in[1];
    const float* wk    = (const float*)d_in[2];
    const float* wv    = (const float*)d_in[3];
    const float* wo    = (const float*)d_in[4];
    const float* sigma = (const float*)d_in[5];

    float* out      = (float*)d_out;                 // [16,256,64,64]
    float* attn_out = out + (size_t)16777216;        // [1024,64,64]

    // x hi/lo bf16 alias the out-image region (dead until out_conv_mfma):
    ushort* xh = (ushort*)d_out;                     // 16,777,216 bf16 = 32 MiB
    ushort* xl = xh + (size_t)16777216;              // 32 MiB (ends at attn_out)

    // d_ws: av | weights | zero page (~17.7 MiB)
    ushort* av  = (ushort*)d_ws;                     // 8,388,608 bf16
    ushort* wvT = av + 8388608;                      // 294,912
    ushort* woT = wvT + 294912;                      // 294,912
    ushort* wqh = woT + 294912;                      // 147,456
    ushort* wql = wqh + 147456;                      // 147,456
    ushort* zp  = wql + 147456;                      // 512 (1 KB zero page)

    repack_w<<<2880, 256, 0, stream>>>(wq, wk, wv, wo, wvT, woT, wqh, wql, zp);
    repack_x2<<<B_ * VDIM, 256, 0, stream>>>(x, xh, xl);
    qkvattn<<<B_ * TDIM, 256, 0, stream>>>(xh, xl, wvT, wqh, wql, zp, attn_out, av);
    out_conv_mfma<<<B_ * VDIM, 512, 0, stream>>>(x, av, woT, zp, sigma, out);
}

// Round 13
// 308.534 us; speedup vs baseline: 1.0443x; 1.0443x over previous
//
#include <hip/hip_runtime.h>
#include <hip/hip_bf16.h>

typedef __hip_bfloat16 bf16;
typedef float f32x4 __attribute__((ext_vector_type(4)));
typedef short s16x8 __attribute__((ext_vector_type(8)));

#define B_   16
#define CIN  256
#define CQK  32
#define CV   128
#define VDIM 64
#define TDIM 64
#define P    (VDIM * TDIM)   // 4096

static __device__ __forceinline__ ushort f2bf(float f) {
    bf16 h = __float2bfloat16(f);
    return *(ushort*)&h;
}
static __device__ __forceinline__ float bf2f(ushort u) {
    bf16 h = *(bf16*)&u;
    return __bfloat162float(h);
}

// async 16B-per-lane global -> LDS DMA (LDS dest = wave-uniform base + lane*16)
static __device__ __forceinline__ void gld16(const void* gsrc, void* ldst) {
    __builtin_amdgcn_global_load_lds(
        (const __attribute__((address_space(1))) void*)gsrc,
        (__attribute__((address_space(3))) void*)ldst,
        16, 0, 0);
}

#define MFMA16(A, B, C) __builtin_amdgcn_mfma_f32_16x16x32_bf16((A), (B), (C), 0, 0, 0)

// ---------------------------------------------------------------------------
// repack_w: weights -> [tap][oc][ci] bf16 (+ hi/lo split for q,k); zero zp page.
// ---------------------------------------------------------------------------
__global__ __launch_bounds__(256) void repack_w(
    const float* __restrict__ wq, const float* __restrict__ wk,
    const float* __restrict__ wv, const float* __restrict__ wo,
    ushort* __restrict__ wvT, ushort* __restrict__ woT,
    ushort* __restrict__ wqh, ushort* __restrict__ wql,
    ushort* __restrict__ zp)
{
    if (blockIdx.x == 0) ((uint*)zp)[threadIdx.x] = 0;   // 1KB zero page
    int i = blockIdx.x * 256 + threadIdx.x;
    const int NQK = 9 * 64 * 256;      // 147456
    const int NV  = 9 * 128 * 256;     // 294912
    if (i < NQK) {
        int tap = i / (64 * 256);
        int r   = i % (64 * 256);
        int oc  = r >> 8;
        int ci  = r & 255;
        const float* src = (oc < 32) ? wq : wk;
        float f = src[(size_t)(oc & 31) * 2304 + ci * 9 + tap];
        ushort h = f2bf(f);
        wqh[i] = h;
        wql[i] = f2bf(f - bf2f(h));
    } else if (i < NQK + NV) {
        i -= NQK;
        int tap = i / (128 * 256);
        int r   = i % (128 * 256);
        int oc  = r >> 8;
        int ci  = r & 255;
        wvT[i] = f2bf(wv[(size_t)oc * 2304 + ci * 9 + tap]);
    } else {
        i -= NQK + NV;
        int tap = i / (256 * 128);
        int r   = i % (256 * 128);
        int oc  = r >> 7;
        int ci  = r & 127;
        woT[i] = f2bf(wo[(size_t)oc * 1152 + ci * 9 + tap]);
    }
}

// ---------------------------------------------------------------------------
// repack_x2: x [B][256][64y][64t] f32 -> xh,xl [B][64t][64y][256ci] bf16
// ---------------------------------------------------------------------------
__global__ __launch_bounds__(256) void repack_x2(
    const float* __restrict__ x, ushort* __restrict__ xhd, ushort* __restrict__ xld)
{
    const int b = blockIdx.x >> 6;
    const int y = blockIdx.x & 63;
    __shared__ ushort th[64][257];
    __shared__ ushort tl_[64][257];
    const int t  = threadIdx.x & 63;
    const int cq = threadIdx.x >> 6;
    const float* xb = x + (((size_t)b * CIN) * VDIM + y) * TDIM;
    for (int ci = cq; ci < 256; ci += 4) {
        float f = xb[(size_t)ci * P + t];
        ushort h = f2bf(f);
        th[t][ci]  = h;
        tl_[t][ci] = f2bf(f - bf2f(h));
    }
    __syncthreads();
    const int ci4 = (threadIdx.x & 63) * 4;
    const int tr0 = threadIdx.x >> 6;
    for (int tr = tr0; tr < 64; tr += 4) {
        ushort4 uh, ul;
        uh.x = th[tr][ci4];     uh.y = th[tr][ci4 + 1];
        uh.z = th[tr][ci4 + 2]; uh.w = th[tr][ci4 + 3];
        ul.x = tl_[tr][ci4];     ul.y = tl_[tr][ci4 + 1];
        ul.z = tl_[tr][ci4 + 2]; ul.w = tl_[tr][ci4 + 3];
        const size_t o = ((((size_t)b * 64 + tr) * 64 + y) * 256 + ci4);
        *(ushort4*)(xhd + o) = uh;
        *(ushort4*)(xld + o) = ul;
    }
}

// ---------------------------------------------------------------------------
// Hoisted-address stage of one [3 dx][66 yl][128 ci] tile via gload_lds.
// Row pointers bp[0..12] + ok-bitmask precomputed ONCE per thread; each stage
// phase is 13x {masked offset add + gld16}. DELTA = ci0 (+ xl offset for the
// lo tensor); zp rows never get the offset. Identical DMA order/layout to R11.
// ---------------------------------------------------------------------------
#define STAGE_P(DELTA)                                                            \
    {                                                                             \
        _Pragma("unroll")                                                         \
        for (int j = 0; j < 13; ++j) {                                            \
            if (j < ni) {                                                         \
                const ushort* sp = bp[j] + (((okm >> j) & 1u) ? (size_t)(DELTA) : 0); \
                gld16(sp, btile + (w * 13 + j) * 1024);                           \
            }                                                                     \
        }                                                                         \
    }

// Read the 4 B-fragments for one tap (dy,dxp) at k-step kk (swizzled read).
#define READ_BFR(BFR, DY, DXP, KK)                                                \
    {                                                                             \
        _Pragma("unroll")                                                         \
        for (int nf = 0; nf < 4; ++nf) {                                          \
            const int ylr = nf * 16 + (lane & 15) + (DY);                         \
            const int row = (DXP) * 66 + ylr;                                     \
            BFR[nf] = *(const s16x8*)(btile + row * 256 +                         \
                       ((((KK) * 64 + (lane >> 4) * 16)) ^ ((row & 7) << 4)));    \
        }                                                                         \
    }

// ---------------------------------------------------------------------------
// qkvattn: fused q/k/v conv (MFMA implicit GEMM) + MFMA attention per (b,t0).
// R11 structure (proven 199.5us): 128-ci chunks, tap-outer/4-kk weight batches,
// 4 stage phases with stage-issue right before drain barrier. This round only
// hoists staging address arithmetic into registers (pure VALU removal;
// bitwise-identical output). R10 issue-early and R12 64-ci variants regressed.
// ---------------------------------------------------------------------------
__global__ __launch_bounds__(256) void qkvattn(
    const ushort* __restrict__ xh, const ushort* __restrict__ xl,
    const ushort* __restrict__ wvT,
    const ushort* __restrict__ wqh, const ushort* __restrict__ wql,
    const ushort* __restrict__ zp,
    float* __restrict__ attn_out, ushort* __restrict__ av)
{
    // XCD-bijective swizzle (1024 blocks, 8 XCDs, 128/XCD)
    const int bid  = ((blockIdx.x & 7) << 7) | (blockIdx.x >> 3);
    const int b    = bid >> 6;
    const int t0   = bid & 63;
    const int tid  = threadIdx.x;
    const int lane = tid & 63;
    const int w    = tid >> 6;

    __shared__ __align__(16) char smem[51200];
    char* btile = smem;

    f32x4 accv[2][4];
    f32x4 accq[4];
#pragma unroll
    for (int m = 0; m < 2; ++m)
#pragma unroll
        for (int nf = 0; nf < 4; ++nf) accv[m][nf] = (f32x4){0.f, 0.f, 0.f, 0.f};
#pragma unroll
    for (int nf = 0; nf < 4; ++nf) accq[nf] = (f32x4){0.f, 0.f, 0.f, 0.f};

    const int ocv  = w * 32 + (lane & 15);        // v channel base (m adds 16)
    const int ocqk = w * 16 + (lane & 15);        // combined q|k channel
    const int ko8  = (lane >> 4) * 8;

    // ---- precompute stage row pointers (26 VGPR) + ok mask, once ----
    const int ni = (w == 3) ? 11 : 13;
    const ushort* bp[13];
    uint okm = 0;
#pragma unroll
    for (int j = 0; j < 13; ++j) {
        const int ii  = w * 13 + j;
        const int row = ii * 4 + (lane >> 4);
        const int dxs = (row * 993) >> 16;
        const int yl  = row - dxs * 66;
        const int tp  = t0 + dxs - 1;
        const int yp  = yl - 1;
        const int chg = (lane & 15) ^ (row & 7);
        const bool ok = ((unsigned)tp < 64u) && ((unsigned)yp < 64u) && (row < 198);
        bp[j] = ok ? (xh + ((((size_t)b * 64 + tp) * 64 + yp) * 256 + chg * 8))
                   : (zp + (size_t)lane * 8);
        okm |= (ok ? 1u : 0u) << j;
    }
    const size_t xloff = (size_t)(xl - xh);

#define WVO(TAP, M, KK) (const s16x8*)(wvT + (size_t)((TAP) * 128 + ocv + (M) * 16) * 256 + ci0 + (KK) * 32 + ko8)
#define WQO(ARR, TAP, KK) (const s16x8*)((ARR) + (size_t)((TAP) * 64 + ocqk) * 256 + ci0 + (KK) * 32 + ko8)

    for (int chunk = 0; chunk < 2; ++chunk) {
        const int ci0 = chunk * 128;

        __syncthreads();              // protect btile from prior readers
        STAGE_P(ci0)                  // xh tile
        __syncthreads();              // drains vmcnt -> DMAs complete

        // ---- merged v + qk-hi pass over x_hi (shared bfr reads) ----
#pragma unroll 1
        for (int tap = 0; tap < 9; ++tap) {
            const int dy = tap / 3, dxp = tap % 3;
            s16x8 va[4], vb[4], ha[4], la[4];
#pragma unroll
            for (int kk = 0; kk < 4; ++kk) {
                va[kk] = *WVO(tap, 0, kk);
                vb[kk] = *WVO(tap, 1, kk);
                ha[kk] = *WQO(wqh, tap, kk);
                la[kk] = *WQO(wql, tap, kk);
            }
#pragma unroll
            for (int kk = 0; kk < 4; ++kk) {
                s16x8 bfr[4];
                READ_BFR(bfr, dy, dxp, kk)
#pragma unroll
                for (int nf = 0; nf < 4; ++nf)
                    accv[0][nf] = MFMA16(va[kk], bfr[nf], accv[0][nf]);
#pragma unroll
                for (int nf = 0; nf < 4; ++nf)
                    accv[1][nf] = MFMA16(vb[kk], bfr[nf], accv[1][nf]);
#pragma unroll
                for (int nf = 0; nf < 4; ++nf)
                    accq[nf] = MFMA16(ha[kk], bfr[nf], accq[nf]);
#pragma unroll
                for (int nf = 0; nf < 4; ++nf)
                    accq[nf] = MFMA16(la[kk], bfr[nf], accq[nf]);
            }
        }

        __syncthreads();              // all reads of x_hi tile done
        STAGE_P(ci0 + xloff)          // xl tile
        __syncthreads();

        // ---- qk lo pass (w_hi . x_lo) ----
#pragma unroll 1
        for (int tap = 0; tap < 9; ++tap) {
            const int dy = tap / 3, dxp = tap % 3;
            s16x8 ha[4];
#pragma unroll
            for (int kk = 0; kk < 4; ++kk) ha[kk] = *WQO(wqh, tap, kk);
#pragma unroll
            for (int kk = 0; kk < 4; ++kk) {
                s16x8 bfr[4];
                READ_BFR(bfr, dy, dxp, kk)
#pragma unroll
                for (int nf = 0; nf < 4; ++nf)
                    accq[nf] = MFMA16(ha[kk], bfr[nf], accq[nf]);
            }
        }
    }
#undef WVO
#undef WQO
    __syncthreads();   // btile dead; repurpose LDS for MFMA attention

    const int l15 = lane & 15, lg = lane >> 4;

    // ---- phase A: conv accumulators -> LDS (q/k bf16 hi/lo, vsT) ----
    {
        char* qkb = smem + ((w < 2) ? 0 : 8192);
        const int c0 = (w & 1) * 16 + lg * 4;
#pragma unroll
        for (int nf = 0; nf < 4; ++nf) {
            const int y = nf * 16 + l15;
            ushort4 h4, l4;
#pragma unroll
            for (int r = 0; r < 4; ++r) {
                ushort h = f2bf(accq[nf][r]);
                ((ushort*)&h4)[r] = h;
                ((ushort*)&l4)[r] = f2bf(accq[nf][r] - bf2f(h));
            }
            const int swz = (y & 7) << 4;
            *(ushort4*)(qkb + y * 128 + ((2 * c0) ^ swz))      = h4;
            *(ushort4*)(qkb + y * 128 + ((64 + 2 * c0) ^ swz)) = l4;
        }
        // vsT[c][j] = v[j][c] (bf16), swizzled rows
#pragma unroll
        for (int m = 0; m < 2; ++m)
#pragma unroll
            for (int nf = 0; nf < 4; ++nf) {
                const int y = nf * 16 + l15;
#pragma unroll
                for (int r = 0; r < 4; ++r) {
                    const int oc = w * 32 + m * 16 + lg * 4 + r;
                    *(ushort*)(smem + 16384 + oc * 128 + ((2 * y) ^ ((oc & 7) << 4)))
                        = f2bf(accv[m][nf][r]);
                }
            }
    }
    __syncthreads();

    // ---- phase B: S via MFMA (3-pass), softmax in-register, attn + P writes ----
    f32x4 pv[4];
    {
        const int yq = w * 16 + l15;
        const int sq = (yq & 7) << 4;
        s16x8 qh = *(const s16x8*)(smem + yq * 128 + ((lg * 16) ^ sq));
        s16x8 ql = *(const s16x8*)(smem + yq * 128 + ((64 + lg * 16) ^ sq));
        f32x4 sAcc[4];
#pragma unroll
        for (int jt = 0; jt < 4; ++jt) {
            const int jr = jt * 16 + l15;
            const int sk = (jr & 7) << 4;
            s16x8 kh = *(const s16x8*)(smem + 8192 + jr * 128 + ((lg * 16) ^ sk));
            s16x8 kl = *(const s16x8*)(smem + 8192 + jr * 128 + ((64 + lg * 16) ^ sk));
            f32x4 a = (f32x4){0.f, 0.f, 0.f, 0.f};
            a = MFMA16(qh, kh, a);
            a = MFMA16(qh, kl, a);
            a = MFMA16(ql, kh, a);
            sAcc[jt] = a;   // S[w*16 + lg*4 + r][jt*16 + l15]
        }
        // softmax over j (= jt x l15): in-register + 16-lane shfl_xor
        float mx[4], sum[4];
#pragma unroll
        for (int r = 0; r < 4; ++r)
            mx[r] = fmaxf(fmaxf(sAcc[0][r], sAcc[1][r]), fmaxf(sAcc[2][r], sAcc[3][r]));
#pragma unroll
        for (int d = 1; d < 16; d <<= 1)
#pragma unroll
            for (int r = 0; r < 4; ++r) mx[r] = fmaxf(mx[r], __shfl_xor(mx[r], d));
#pragma unroll
        for (int r = 0; r < 4; ++r) sum[r] = 0.f;
#pragma unroll
        for (int jt = 0; jt < 4; ++jt)
#pragma unroll
            for (int r = 0; r < 4; ++r) {
                pv[jt][r] = expf(sAcc[jt][r] - mx[r]);
                sum[r] += pv[jt][r];
            }
#pragma unroll
        for (int d = 1; d < 16; d <<= 1)
#pragma unroll
            for (int r = 0; r < 4; ++r) sum[r] += __shfl_xor(sum[r], d);
#pragma unroll
        for (int r = 0; r < 4; ++r) sum[r] = 1.f / sum[r];
#pragma unroll
        for (int jt = 0; jt < 4; ++jt)
#pragma unroll
            for (int r = 0; r < 4; ++r) pv[jt][r] *= sum[r];

        // attn write (fp32)
        float* ao = attn_out + (size_t)bid * 4096;
#pragma unroll
        for (int jt = 0; jt < 4; ++jt)
#pragma unroll
            for (int r = 0; r < 4; ++r)
                ao[(w * 16 + lg * 4 + r) * 64 + jt * 16 + l15] = pv[jt][r];

        // P -> bf16 hi/lo LDS [i][j] swizzled rows
#pragma unroll
        for (int jt = 0; jt < 4; ++jt)
#pragma unroll
            for (int r = 0; r < 4; ++r) {
                const int i = w * 16 + lg * 4 + r;
                const int j = jt * 16 + l15;
                const int off = i * 128 + ((2 * j) ^ ((i & 7) << 4));
                ushort h = f2bf(pv[jt][r]);
                *(ushort*)(smem + 32768 + off) = h;
                *(ushort*)(smem + 40960 + off) = f2bf(pv[jt][r] - bf2f(h));
            }
    }
    __syncthreads();

    // ---- phase C: AV^T = V^T (Phi + Plo) via MFMA; avL (reuses q/k bytes) ----
    {
        f32x4 acc2[2][4];
#pragma unroll
        for (int c2 = 0; c2 < 2; ++c2)
#pragma unroll
            for (int it = 0; it < 4; ++it) acc2[c2][it] = (f32x4){0.f, 0.f, 0.f, 0.f};

        s16x8 vt[2][2];
#pragma unroll
        for (int c2 = 0; c2 < 2; ++c2)
#pragma unroll
            for (int ks = 0; ks < 2; ++ks) {
                const int c = (w * 2 + c2) * 16 + l15;
                vt[c2][ks] = *(const s16x8*)(smem + 16384 + c * 128 +
                                             ((ks * 64 + lg * 16) ^ ((c & 7) << 4)));
            }
#pragma unroll
        for (int it = 0; it < 4; ++it) {
            const int i = it * 16 + l15;
            const int si = (i & 7) << 4;
            s16x8 ph[2], pl[2];
#pragma unroll
            for (int ks = 0; ks < 2; ++ks) {
                ph[ks] = *(const s16x8*)(smem + 32768 + i * 128 + ((ks * 64 + lg * 16) ^ si));
                pl[ks] = *(const s16x8*)(smem + 40960 + i * 128 + ((ks * 64 + lg * 16) ^ si));
            }
#pragma unroll
            for (int c2 = 0; c2 < 2; ++c2)
#pragma unroll
                for (int ks = 0; ks < 2; ++ks) {
                    acc2[c2][it] = MFMA16(vt[c2][ks], ph[ks], acc2[c2][it]);
                    acc2[c2][it] = MFMA16(vt[c2][ks], pl[ks], acc2[c2][it]);
                }
        }
        // avL[i][c] (bf16) swizzled [64][256B] rows at bytes [0,16384)
#pragma unroll
        for (int c2 = 0; c2 < 2; ++c2)
#pragma unroll
            for (int it = 0; it < 4; ++it)
#pragma unroll
                for (int r = 0; r < 4; ++r) {
                    const int c = (w * 2 + c2) * 16 + lg * 4 + r;
                    const int i = it * 16 + l15;
                    *(ushort*)(smem + i * 256 + ((2 * c) ^ ((i & 7) << 4)))
                        = f2bf(acc2[c2][it][r]);
                }
    }
    __syncthreads();

    // ---- phase D: avL -> global, fully coalesced ----
    {
        uint* avg = (uint*)(av + (size_t)bid * 8192);
#pragma unroll
        for (int t = 0; t < 16; ++t) {
            const int idx = t * 256 + tid;
            const int i  = idx >> 6;
            const int cc = idx & 63;
            avg[idx] = *(const uint*)(smem + i * 256 + ((4 * cc) ^ ((i & 7) << 4)));
        }
    }
}

// ---------------------------------------------------------------------------
// out_conv_mfma: 512-thread / 8-wave block = (b,y): M=256 oc, N=64 t,
// K=128ci*9tap. av-halo tile staged ONCE per (b,y). (R11, unchanged)
// ---------------------------------------------------------------------------
__global__ __launch_bounds__(512) void out_conv_mfma(
    const float* __restrict__ x,
    const ushort* __restrict__ av,
    const ushort* __restrict__ woT,
    const ushort* __restrict__ zp,
    const float* __restrict__ sigma,
    float* __restrict__ out)
{
    // XCD-bijective swizzle (1024 blocks, 128/XCD)
    const int bid  = ((blockIdx.x & 7) << 7) | (blockIdx.x >> 3);
    const int y    = bid & 63;
    const int b    = bid >> 6;
    const int tid  = threadIdx.x;
    const int lane = tid & 63;
    const int w    = tid >> 6;           // 0..7

    __shared__ __align__(16) char smem[51200];
    char* btile = smem;

    f32x4 acc[2][4];
#pragma unroll
    for (int m = 0; m < 2; ++m)
#pragma unroll
        for (int nf = 0; nf < 4; ++nf) acc[m][nf] = (f32x4){0.f, 0.f, 0.f, 0.f};

    // stage [3 dy][66 tl][128 ci] from av via gload_lds (swizzle in source);
    // 50 DMA rows split 7/7/6/6/6/6/6/6 across 8 waves.
    {
        const int i0 = (w < 2) ? w * 7 : 14 + (w - 2) * 6;
        const int ni = (w < 2) ? 7 : 6;
        for (int j = 0; j < ni; ++j) {
            const int ii  = i0 + j;
            const int row = ii * 4 + (lane >> 4);
            const int dys = (row * 993) >> 16;
            const int tl  = row - dys * 66;
            const int yp  = y + dys - 1;
            const int tp  = tl - 1;
            const int chg = (lane & 15) ^ (row & 7);
            const bool ok = ((unsigned)yp < 64u) && ((unsigned)tp < 64u) && (row < 198);
            const ushort* sp = ok
                ? av + ((((size_t)b * 64 + tp) * 64 + yp) * 128 + chg * 8)
                : zp + (size_t)lane * 8;
            gld16(sp, btile + ii * 1024);
        }
    }
    __syncthreads();

    const int oc  = w * 32 + (lane & 15);
    const int ko8 = (lane >> 4) * 8;
#define WOO(TAP, M, KK) (const s16x8*)(woT + (size_t)((TAP) * 256 + oc + (M) * 16) * 128 + (KK) * 32 + ko8)
#pragma unroll 1
    for (int tap = 0; tap < 9; ++tap) {
        const int dy = tap / 3, dxp = tap % 3;
        s16x8 wa[4], wb[4];
#pragma unroll
        for (int kk = 0; kk < 4; ++kk) {
            wa[kk] = *WOO(tap, 0, kk);
            wb[kk] = *WOO(tap, 1, kk);
        }
#pragma unroll
        for (int kk = 0; kk < 4; ++kk) {
            s16x8 bfr[4];
#pragma unroll
            for (int nf = 0; nf < 4; ++nf) {
                const int tl = nf * 16 + (lane & 15) + dxp;
                const int row = dy * 66 + tl;
                const int bir = kk * 64 + (lane >> 4) * 16;
                bfr[nf] = *(const s16x8*)(btile + row * 256 + (bir ^ ((row & 7) << 4)));
            }
#pragma unroll
            for (int nf = 0; nf < 4; ++nf)
                acc[0][nf] = MFMA16(wa[kk], bfr[nf], acc[0][nf]);
#pragma unroll
            for (int nf = 0; nf < 4; ++nf)
                acc[1][nf] = MFMA16(wb[kk], bfr[nf], acc[1][nf]);
        }
    }
#undef WOO

    const float s = sigma[0];
#pragma unroll
    for (int m = 0; m < 2; ++m)
#pragma unroll
        for (int nf = 0; nf < 4; ++nf)
#pragma unroll
            for (int r = 0; r < 4; ++r) {
                const int occ = w * 32 + m * 16 + (lane >> 4) * 4 + r;
                const int t   = nf * 16 + (lane & 15);
                const size_t a = (((size_t)b * 256 + occ) * 64 + y) * 64 + t;
                out[a] = x[a] + s * acc[m][nf][r];
            }
}

// ---------------------------------------------------------------------------
extern "C" void kernel_launch(void* const* d_in, const int* in_sizes, int n_in,
                              void* d_out, int out_size, void* d_ws, size_t ws_size,
                              hipStream_t stream)
{
    const float* x     = (const float*)d_in[0];
    const float* wq    = (const float*)d_in[1];
    const float* wk    = (const float*)d_in[2];
    const float* wv    = (const float*)d_in[3];
    const float* wo    = (const float*)d_in[4];
    const float* sigma = (const float*)d_in[5];

    float* out      = (float*)d_out;                 // [16,256,64,64]
    float* attn_out = out + (size_t)16777216;        // [1024,64,64]

    // x hi/lo bf16 alias the out-image region (dead until out_conv_mfma):
    ushort* xh = (ushort*)d_out;                     // 16,777,216 bf16 = 32 MiB
    ushort* xl = xh + (size_t)16777216;              // 32 MiB (ends at attn_out)

    // d_ws: av | weights | zero page (~17.7 MiB)
    ushort* av  = (ushort*)d_ws;                     // 8,388,608 bf16
    ushort* wvT = av + 8388608;                      // 294,912
    ushort* woT = wvT + 294912;                      // 294,912
    ushort* wqh = woT + 294912;                      // 147,456
    ushort* wql = wqh + 147456;                      // 147,456
    ushort* zp  = wql + 147456;                      // 512 (1 KB zero page)

    repack_w<<<2880, 256, 0, stream>>>(wq, wk, wv, wo, wvT, woT, wqh, wql, zp);
    repack_x2<<<B_ * VDIM, 256, 0, stream>>>(x, xh, xl);
    qkvattn<<<B_ * TDIM, 256, 0, stream>>>(xh, xl, wvT, wqh, wql, zp, attn_out, av);
    out_conv_mfma<<<B_ * VDIM, 512, 0, stream>>>(x, av, woT, zp, sigma, out);
}

// Round 14
// 229.595 us; speedup vs baseline: 1.4033x; 1.3438x over previous
//
#include <hip/hip_runtime.h>
#include <hip/hip_bf16.h>

typedef __hip_bfloat16 bf16;
typedef float f32x4 __attribute__((ext_vector_type(4)));
typedef short s16x8 __attribute__((ext_vector_type(8)));

#define B_   16
#define CIN  256
#define CQK  32
#define CV   128
#define VDIM 64
#define TDIM 64
#define P    (VDIM * TDIM)   // 4096

static __device__ __forceinline__ ushort f2bf(float f) {
    bf16 h = __float2bfloat16(f);
    return *(ushort*)&h;
}
static __device__ __forceinline__ float bf2f(ushort u) {
    bf16 h = *(bf16*)&u;
    return __bfloat162float(h);
}

// async 16B-per-lane global -> LDS DMA (LDS dest = wave-uniform base + lane*16)
static __device__ __forceinline__ void gld16(const void* gsrc, void* ldst) {
    __builtin_amdgcn_global_load_lds(
        (const __attribute__((address_space(1))) void*)gsrc,
        (__attribute__((address_space(3))) void*)ldst,
        16, 0, 0);
}

#define MFMA16(A, B, C) __builtin_amdgcn_mfma_f32_16x16x32_bf16((A), (B), (C), 0, 0, 0)

// ---------------------------------------------------------------------------
// repack_w: weights -> [tap][oc][ci] bf16 (+ hi/lo split for q,k); zero zp page.
// ---------------------------------------------------------------------------
__global__ __launch_bounds__(256) void repack_w(
    const float* __restrict__ wq, const float* __restrict__ wk,
    const float* __restrict__ wv, const float* __restrict__ wo,
    ushort* __restrict__ wvT, ushort* __restrict__ woT,
    ushort* __restrict__ wqh, ushort* __restrict__ wql,
    ushort* __restrict__ zp)
{
    if (blockIdx.x == 0) ((uint*)zp)[threadIdx.x] = 0;   // 1KB zero page
    int i = blockIdx.x * 256 + threadIdx.x;
    const int NQK = 9 * 64 * 256;      // 147456
    const int NV  = 9 * 128 * 256;     // 294912
    if (i < NQK) {
        int tap = i / (64 * 256);
        int r   = i % (64 * 256);
        int oc  = r >> 8;
        int ci  = r & 255;
        const float* src = (oc < 32) ? wq : wk;
        float f = src[(size_t)(oc & 31) * 2304 + ci * 9 + tap];
        ushort h = f2bf(f);
        wqh[i] = h;
        wql[i] = f2bf(f - bf2f(h));
    } else if (i < NQK + NV) {
        i -= NQK;
        int tap = i / (128 * 256);
        int r   = i % (128 * 256);
        int oc  = r >> 8;
        int ci  = r & 255;
        wvT[i] = f2bf(wv[(size_t)oc * 2304 + ci * 9 + tap]);
    } else {
        i -= NQK + NV;
        int tap = i / (256 * 128);
        int r   = i % (256 * 128);
        int oc  = r >> 7;
        int ci  = r & 127;
        woT[i] = f2bf(wo[(size_t)oc * 1152 + ci * 9 + tap]);
    }
}

// ---------------------------------------------------------------------------
// repack_x2: x [B][256][64y][64t] f32 -> xh,xl [B][64t][64y][256ci] bf16
// ---------------------------------------------------------------------------
__global__ __launch_bounds__(256) void repack_x2(
    const float* __restrict__ x, ushort* __restrict__ xhd, ushort* __restrict__ xld)
{
    const int b = blockIdx.x >> 6;
    const int y = blockIdx.x & 63;
    __shared__ ushort th[64][257];
    __shared__ ushort tl_[64][257];
    const int t  = threadIdx.x & 63;
    const int cq = threadIdx.x >> 6;
    const float* xb = x + (((size_t)b * CIN) * VDIM + y) * TDIM;
    for (int ci = cq; ci < 256; ci += 4) {
        float f = xb[(size_t)ci * P + t];
        ushort h = f2bf(f);
        th[t][ci]  = h;
        tl_[t][ci] = f2bf(f - bf2f(h));
    }
    __syncthreads();
    const int ci4 = (threadIdx.x & 63) * 4;
    const int tr0 = threadIdx.x >> 6;
    for (int tr = tr0; tr < 64; tr += 4) {
        ushort4 uh, ul;
        uh.x = th[tr][ci4];     uh.y = th[tr][ci4 + 1];
        uh.z = th[tr][ci4 + 2]; uh.w = th[tr][ci4 + 3];
        ul.x = tl_[tr][ci4];     ul.y = tl_[tr][ci4 + 1];
        ul.z = tl_[tr][ci4 + 2]; ul.w = tl_[tr][ci4 + 3];
        const size_t o = ((((size_t)b * 64 + tr) * 64 + y) * 256 + ci4);
        *(ushort4*)(xhd + o) = uh;
        *(ushort4*)(xld + o) = ul;
    }
}

// ---------------------------------------------------------------------------
// Stage one [4 dx][66 yl][128 ci] tile (264 rows x 256B = 67.6KB) via gload_lds.
// dx spans t0-1 .. t0+2 (shared halo for the 2-column block). 66 DMA instrs
// split 17/17/16/16 across waves. Swizzle folded into source channel.
// ---------------------------------------------------------------------------
#define STAGE2(SRC, CI0)                                                          \
    {                                                                             \
        const int i0 = (w < 2) ? w * 17 : 34 + (w - 2) * 16;                      \
        const int nr = (w < 2) ? 17 : 16;                                         \
        for (int j = 0; j < nr; ++j) {                                            \
            const int ii  = i0 + j;                                               \
            const int row = ii * 4 + (lane >> 4);                                 \
            const int dxs = (row * 993) >> 16;                                    \
            const int yl  = row - dxs * 66;                                       \
            const int tp  = t0 + dxs - 1;                                         \
            const int yp  = yl - 1;                                               \
            const int chg = (lane & 15) ^ (row & 7);                              \
            const bool ok = ((unsigned)tp < 64u) && ((unsigned)yp < 64u);         \
            const ushort* sp = ok                                                 \
                ? (SRC) + ((((size_t)b * 64 + tp) * 64 + yp) * 256 + (CI0) + chg * 8) \
                : zp + (size_t)lane * 8;                                          \
            gld16(sp, btile + ii * 1024);                                         \
        }                                                                         \
    }

// Read the 4 B-fragments for dx-slice DXS (0..3) at k-step kk (swizzled read).
#define READ_BFR(BFR, DY, DXS, KK)                                                \
    {                                                                             \
        _Pragma("unroll")                                                         \
        for (int nf = 0; nf < 4; ++nf) {                                          \
            const int ylr = nf * 16 + (lane & 15) + (DY);                         \
            const int row = (DXS) * 66 + ylr;                                     \
            BFR[nf] = *(const s16x8*)(btile + row * 256 +                         \
                       ((((KK) * 64 + (lane >> 4) * 16)) ^ ((row & 7) << 4)));    \
        }                                                                         \
    }

// ---------------------------------------------------------------------------
// qkvattn2: fused q/k/v conv + MFMA attention, TWO t-columns per block.
// Block = (b, t-pair): stage [4dx][66][128ci] once (shared halo); each wave's
// weight batch (16 frags) feeds 32 MFMA (col0+col1) per kk -> weight L2
// traffic halved, per-tap latency amortized 2x, barriers per work halved.
// Per-column MFMA order identical to R11/R13 -> bitwise-identical output.
// Tail: R12 compressed 32KB layout, run per column (unrolled -> static idx).
// ---------------------------------------------------------------------------
__global__ __launch_bounds__(256) void qkvattn2(
    const ushort* __restrict__ xh, const ushort* __restrict__ xl,
    const ushort* __restrict__ wvT,
    const ushort* __restrict__ wqh, const ushort* __restrict__ wql,
    const ushort* __restrict__ zp,
    float* __restrict__ attn_out, ushort* __restrict__ av)
{
    // XCD-bijective swizzle (512 blocks, 8 XCDs, 64/XCD)
    const int bid  = ((blockIdx.x & 7) << 6) | (blockIdx.x >> 3);
    const int b    = bid >> 5;
    const int t0   = (bid & 31) * 2;
    const int tid  = threadIdx.x;
    const int lane = tid & 63;
    const int w    = tid >> 6;

    __shared__ __align__(16) char smem[67584];
    char* btile = smem;

    f32x4 accv[2][2][4];   // [col][m][nf]
    f32x4 accq[2][4];      // [col][nf]
#pragma unroll
    for (int c = 0; c < 2; ++c) {
#pragma unroll
        for (int m = 0; m < 2; ++m)
#pragma unroll
            for (int nf = 0; nf < 4; ++nf) accv[c][m][nf] = (f32x4){0.f, 0.f, 0.f, 0.f};
#pragma unroll
        for (int nf = 0; nf < 4; ++nf) accq[c][nf] = (f32x4){0.f, 0.f, 0.f, 0.f};
    }

    const int ocv  = w * 32 + (lane & 15);        // v channel base (m adds 16)
    const int ocqk = w * 16 + (lane & 15);        // combined q|k channel
    const int ko8  = (lane >> 4) * 8;

#define WVO(TAP, M, KK) (const s16x8*)(wvT + (size_t)((TAP) * 128 + ocv + (M) * 16) * 256 + ci0 + (KK) * 32 + ko8)
#define WQO(ARR, TAP, KK) (const s16x8*)((ARR) + (size_t)((TAP) * 64 + ocqk) * 256 + ci0 + (KK) * 32 + ko8)

    for (int chunk = 0; chunk < 2; ++chunk) {
        const int ci0 = chunk * 128;

        __syncthreads();              // protect btile from prior readers
        STAGE2(xh, ci0)
        __syncthreads();              // drains vmcnt -> DMAs complete

        // ---- merged v + qk-hi pass over x_hi: one weight batch, 2 columns ----
#pragma unroll 1
        for (int tap = 0; tap < 9; ++tap) {
            const int dy = tap / 3, dxp = tap % 3;
            s16x8 va[4], vb[4], ha[4], la[4];
#pragma unroll
            for (int kk = 0; kk < 4; ++kk) {
                va[kk] = *WVO(tap, 0, kk);
                vb[kk] = *WVO(tap, 1, kk);
                ha[kk] = *WQO(wqh, tap, kk);
                la[kk] = *WQO(wql, tap, kk);
            }
#pragma unroll
            for (int kk = 0; kk < 4; ++kk) {
                s16x8 bfr[4];
                READ_BFR(bfr, dy, dxp, kk)          // column 0
#pragma unroll
                for (int nf = 0; nf < 4; ++nf)
                    accv[0][0][nf] = MFMA16(va[kk], bfr[nf], accv[0][0][nf]);
#pragma unroll
                for (int nf = 0; nf < 4; ++nf)
                    accv[0][1][nf] = MFMA16(vb[kk], bfr[nf], accv[0][1][nf]);
#pragma unroll
                for (int nf = 0; nf < 4; ++nf)
                    accq[0][nf] = MFMA16(ha[kk], bfr[nf], accq[0][nf]);
#pragma unroll
                for (int nf = 0; nf < 4; ++nf)
                    accq[0][nf] = MFMA16(la[kk], bfr[nf], accq[0][nf]);

                s16x8 bfr1[4];
                READ_BFR(bfr1, dy, dxp + 1, kk)     // column 1 (same weights)
#pragma unroll
                for (int nf = 0; nf < 4; ++nf)
                    accv[1][0][nf] = MFMA16(va[kk], bfr1[nf], accv[1][0][nf]);
#pragma unroll
                for (int nf = 0; nf < 4; ++nf)
                    accv[1][1][nf] = MFMA16(vb[kk], bfr1[nf], accv[1][1][nf]);
#pragma unroll
                for (int nf = 0; nf < 4; ++nf)
                    accq[1][nf] = MFMA16(ha[kk], bfr1[nf], accq[1][nf]);
#pragma unroll
                for (int nf = 0; nf < 4; ++nf)
                    accq[1][nf] = MFMA16(la[kk], bfr1[nf], accq[1][nf]);
            }
        }

        __syncthreads();              // all reads of x_hi tile done
        STAGE2(xl, ci0)
        __syncthreads();

        // ---- qk lo pass (w_hi . x_lo), 2 columns per weight batch ----
#pragma unroll 1
        for (int tap = 0; tap < 9; ++tap) {
            const int dy = tap / 3, dxp = tap % 3;
            s16x8 ha[4];
#pragma unroll
            for (int kk = 0; kk < 4; ++kk) ha[kk] = *WQO(wqh, tap, kk);
#pragma unroll
            for (int kk = 0; kk < 4; ++kk) {
                s16x8 bfr[4];
                READ_BFR(bfr, dy, dxp, kk)
#pragma unroll
                for (int nf = 0; nf < 4; ++nf)
                    accq[0][nf] = MFMA16(ha[kk], bfr[nf], accq[0][nf]);
                s16x8 bfr1[4];
                READ_BFR(bfr1, dy, dxp + 1, kk)
#pragma unroll
                for (int nf = 0; nf < 4; ++nf)
                    accq[1][nf] = MFMA16(ha[kk], bfr1[nf], accq[1][nf]);
            }
        }
    }
#undef WVO
#undef WQO
    __syncthreads();   // btile dead; repurpose LDS for MFMA attention

    const int l15 = lane & 15, lg = lane >> 4;

    // ---- attention tail, per column (R12 compressed 32KB layout) ----
#pragma unroll
    for (int col = 0; col < 2; ++col) {
        // phase A: conv accumulators -> LDS (q@0 / k@8192 hi|lo, vsT@16384)
        {
            char* qkb = smem + ((w < 2) ? 0 : 8192);
            const int c0 = (w & 1) * 16 + lg * 4;
#pragma unroll
            for (int nf = 0; nf < 4; ++nf) {
                const int y = nf * 16 + l15;
                ushort4 h4, l4;
#pragma unroll
                for (int r = 0; r < 4; ++r) {
                    ushort h = f2bf(accq[col][nf][r]);
                    ((ushort*)&h4)[r] = h;
                    ((ushort*)&l4)[r] = f2bf(accq[col][nf][r] - bf2f(h));
                }
                const int swz = (y & 7) << 4;
                *(ushort4*)(qkb + y * 128 + ((2 * c0) ^ swz))      = h4;
                *(ushort4*)(qkb + y * 128 + ((64 + 2 * c0) ^ swz)) = l4;
            }
#pragma unroll
            for (int m = 0; m < 2; ++m)
#pragma unroll
                for (int nf = 0; nf < 4; ++nf) {
                    const int y = nf * 16 + l15;
#pragma unroll
                    for (int r = 0; r < 4; ++r) {
                        const int oc = w * 32 + m * 16 + lg * 4 + r;
                        *(ushort*)(smem + 16384 + oc * 128 + ((2 * y) ^ ((oc & 7) << 4)))
                            = f2bf(accv[col][m][nf][r]);
                    }
                }
        }
        __syncthreads();

        // phase B: S via MFMA (3-pass), softmax in-register; P overlays q/k
        f32x4 pv[4];
        {
            const int yq = w * 16 + l15;
            const int sq = (yq & 7) << 4;
            s16x8 qh = *(const s16x8*)(smem + yq * 128 + ((lg * 16) ^ sq));
            s16x8 ql = *(const s16x8*)(smem + yq * 128 + ((64 + lg * 16) ^ sq));
            s16x8 kh[4], kl[4];
#pragma unroll
            for (int jt = 0; jt < 4; ++jt) {
                const int jr = jt * 16 + l15;
                const int sk = (jr & 7) << 4;
                kh[jt] = *(const s16x8*)(smem + 8192 + jr * 128 + ((lg * 16) ^ sk));
                kl[jt] = *(const s16x8*)(smem + 8192 + jr * 128 + ((64 + lg * 16) ^ sk));
            }
            __syncthreads();   // ALL q/k reads complete -> safe to overlay P

            f32x4 sAcc[4];
#pragma unroll
            for (int jt = 0; jt < 4; ++jt) {
                f32x4 a = (f32x4){0.f, 0.f, 0.f, 0.f};
                a = MFMA16(qh, kh[jt], a);
                a = MFMA16(qh, kl[jt], a);
                a = MFMA16(ql, kh[jt], a);
                sAcc[jt] = a;
            }
            float mx[4], sum[4];
#pragma unroll
            for (int r = 0; r < 4; ++r)
                mx[r] = fmaxf(fmaxf(sAcc[0][r], sAcc[1][r]), fmaxf(sAcc[2][r], sAcc[3][r]));
#pragma unroll
            for (int d = 1; d < 16; d <<= 1)
#pragma unroll
                for (int r = 0; r < 4; ++r) mx[r] = fmaxf(mx[r], __shfl_xor(mx[r], d));
#pragma unroll
            for (int r = 0; r < 4; ++r) sum[r] = 0.f;
#pragma unroll
            for (int jt = 0; jt < 4; ++jt)
#pragma unroll
                for (int r = 0; r < 4; ++r) {
                    pv[jt][r] = expf(sAcc[jt][r] - mx[r]);
                    sum[r] += pv[jt][r];
                }
#pragma unroll
            for (int d = 1; d < 16; d <<= 1)
#pragma unroll
                for (int r = 0; r < 4; ++r) sum[r] += __shfl_xor(sum[r], d);
#pragma unroll
            for (int r = 0; r < 4; ++r) sum[r] = 1.f / sum[r];
#pragma unroll
            for (int jt = 0; jt < 4; ++jt)
#pragma unroll
                for (int r = 0; r < 4; ++r) pv[jt][r] *= sum[r];

            float* ao = attn_out + (size_t)(b * 64 + t0 + col) * 4096;
#pragma unroll
            for (int jt = 0; jt < 4; ++jt)
#pragma unroll
                for (int r = 0; r < 4; ++r)
                    ao[(w * 16 + lg * 4 + r) * 64 + jt * 16 + l15] = pv[jt][r];

#pragma unroll
            for (int jt = 0; jt < 4; ++jt)
#pragma unroll
                for (int r = 0; r < 4; ++r) {
                    const int i = w * 16 + lg * 4 + r;
                    const int j = jt * 16 + l15;
                    const int off = i * 128 + ((2 * j) ^ ((i & 7) << 4));
                    ushort h = f2bf(pv[jt][r]);
                    *(ushort*)(smem + off)        = h;
                    *(ushort*)(smem + 8192 + off) = f2bf(pv[jt][r] - bf2f(h));
                }
        }
        __syncthreads();

        // phase C: AV^T = V^T (Phi + Plo) via MFMA; avL overlays vsT
        {
            s16x8 vt[2][2];
#pragma unroll
            for (int c2 = 0; c2 < 2; ++c2)
#pragma unroll
                for (int ks = 0; ks < 2; ++ks) {
                    const int c = (w * 2 + c2) * 16 + l15;
                    vt[c2][ks] = *(const s16x8*)(smem + 16384 + c * 128 +
                                                 ((ks * 64 + lg * 16) ^ ((c & 7) << 4)));
                }
            __syncthreads();   // ALL vsT reads complete -> safe to overlay avL

            f32x4 acc2[2][4];
#pragma unroll
            for (int c2 = 0; c2 < 2; ++c2)
#pragma unroll
                for (int it = 0; it < 4; ++it) acc2[c2][it] = (f32x4){0.f, 0.f, 0.f, 0.f};

#pragma unroll
            for (int it = 0; it < 4; ++it) {
                const int i = it * 16 + l15;
                const int si = (i & 7) << 4;
                s16x8 ph[2], pl[2];
#pragma unroll
                for (int ks = 0; ks < 2; ++ks) {
                    ph[ks] = *(const s16x8*)(smem + i * 128 + ((ks * 64 + lg * 16) ^ si));
                    pl[ks] = *(const s16x8*)(smem + 8192 + i * 128 + ((ks * 64 + lg * 16) ^ si));
                }
#pragma unroll
                for (int c2 = 0; c2 < 2; ++c2)
#pragma unroll
                    for (int ks = 0; ks < 2; ++ks) {
                        acc2[c2][it] = MFMA16(vt[c2][ks], ph[ks], acc2[c2][it]);
                        acc2[c2][it] = MFMA16(vt[c2][ks], pl[ks], acc2[c2][it]);
                    }
            }
#pragma unroll
            for (int c2 = 0; c2 < 2; ++c2)
#pragma unroll
                for (int it = 0; it < 4; ++it)
#pragma unroll
                    for (int r = 0; r < 4; ++r) {
                        const int c = (w * 2 + c2) * 16 + lg * 4 + r;
                        const int i = it * 16 + l15;
                        *(ushort*)(smem + 16384 + i * 256 + ((2 * c) ^ ((i & 7) << 4)))
                            = f2bf(acc2[c2][it][r]);
                    }
        }
        __syncthreads();

        // phase D: avL -> global, fully coalesced
        {
            uint* avg = (uint*)(av + (size_t)(b * 64 + t0 + col) * 8192);
#pragma unroll
            for (int t = 0; t < 16; ++t) {
                const int idx = t * 256 + tid;
                const int i  = idx >> 6;
                const int cc = idx & 63;
                avg[idx] = *(const uint*)(smem + 16384 + i * 256 + ((4 * cc) ^ ((i & 7) << 4)));
            }
        }
        __syncthreads();   // protects next column's phase A overlay
    }
}

// ---------------------------------------------------------------------------
// out_conv_mfma: 512-thread / 8-wave block = (b,y): M=256 oc, N=64 t,
// K=128ci*9tap. av-halo tile staged ONCE per (b,y). (R11, unchanged)
// ---------------------------------------------------------------------------
__global__ __launch_bounds__(512) void out_conv_mfma(
    const float* __restrict__ x,
    const ushort* __restrict__ av,
    const ushort* __restrict__ woT,
    const ushort* __restrict__ zp,
    const float* __restrict__ sigma,
    float* __restrict__ out)
{
    // XCD-bijective swizzle (1024 blocks, 128/XCD)
    const int bid  = ((blockIdx.x & 7) << 7) | (blockIdx.x >> 3);
    const int y    = bid & 63;
    const int b    = bid >> 6;
    const int tid  = threadIdx.x;
    const int lane = tid & 63;
    const int w    = tid >> 6;           // 0..7

    __shared__ __align__(16) char smem[51200];
    char* btile = smem;

    f32x4 acc[2][4];
#pragma unroll
    for (int m = 0; m < 2; ++m)
#pragma unroll
        for (int nf = 0; nf < 4; ++nf) acc[m][nf] = (f32x4){0.f, 0.f, 0.f, 0.f};

    // stage [3 dy][66 tl][128 ci] from av via gload_lds (swizzle in source);
    // 50 DMA rows split 7/7/6/6/6/6/6/6 across 8 waves.
    {
        const int i0 = (w < 2) ? w * 7 : 14 + (w - 2) * 6;
        const int ni = (w < 2) ? 7 : 6;
        for (int j = 0; j < ni; ++j) {
            const int ii  = i0 + j;
            const int row = ii * 4 + (lane >> 4);
            const int dys = (row * 993) >> 16;
            const int tl  = row - dys * 66;
            const int yp  = y + dys - 1;
            const int tp  = tl - 1;
            const int chg = (lane & 15) ^ (row & 7);
            const bool ok = ((unsigned)yp < 64u) && ((unsigned)tp < 64u) && (row < 198);
            const ushort* sp = ok
                ? av + ((((size_t)b * 64 + tp) * 64 + yp) * 128 + chg * 8)
                : zp + (size_t)lane * 8;
            gld16(sp, btile + ii * 1024);
        }
    }
    __syncthreads();

    const int oc  = w * 32 + (lane & 15);
    const int ko8 = (lane >> 4) * 8;
#define WOO(TAP, M, KK) (const s16x8*)(woT + (size_t)((TAP) * 256 + oc + (M) * 16) * 128 + (KK) * 32 + ko8)
#pragma unroll 1
    for (int tap = 0; tap < 9; ++tap) {
        const int dy = tap / 3, dxp = tap % 3;
        s16x8 wa[4], wb[4];
#pragma unroll
        for (int kk = 0; kk < 4; ++kk) {
            wa[kk] = *WOO(tap, 0, kk);
            wb[kk] = *WOO(tap, 1, kk);
        }
#pragma unroll
        for (int kk = 0; kk < 4; ++kk) {
            s16x8 bfr[4];
#pragma unroll
            for (int nf = 0; nf < 4; ++nf) {
                const int tl = nf * 16 + (lane & 15) + dxp;
                const int row = dy * 66 + tl;
                const int bir = kk * 64 + (lane >> 4) * 16;
                bfr[nf] = *(const s16x8*)(btile + row * 256 + (bir ^ ((row & 7) << 4)));
            }
#pragma unroll
            for (int nf = 0; nf < 4; ++nf)
                acc[0][nf] = MFMA16(wa[kk], bfr[nf], acc[0][nf]);
#pragma unroll
            for (int nf = 0; nf < 4; ++nf)
                acc[1][nf] = MFMA16(wb[kk], bfr[nf], acc[1][nf]);
        }
    }
#undef WOO

    const float s = sigma[0];
#pragma unroll
    for (int m = 0; m < 2; ++m)
#pragma unroll
        for (int nf = 0; nf < 4; ++nf)
#pragma unroll
            for (int r = 0; r < 4; ++r) {
                const int occ = w * 32 + m * 16 + (lane >> 4) * 4 + r;
                const int t   = nf * 16 + (lane & 15);
                const size_t a = (((size_t)b * 256 + occ) * 64 + y) * 64 + t;
                out[a] = x[a] + s * acc[m][nf][r];
            }
}

// ---------------------------------------------------------------------------
extern "C" void kernel_launch(void* const* d_in, const int* in_sizes, int n_in,
                              void* d_out, int out_size, void* d_ws, size_t ws_size,
                              hipStream_t stream)
{
    const float* x     = (const float*)d_in[0];
    const float* wq    = (const float*)d_in[1];
    const float* wk    = (const float*)d_in[2];
    const float* wv    = (const float*)d_in[3];
    const float* wo    = (const float*)d_in[4];
    const float* sigma = (const float*)d_in[5];

    float* out      = (float*)d_out;                 // [16,256,64,64]
    float* attn_out = out + (size_t)16777216;        // [1024,64,64]

    // x hi/lo bf16 alias the out-image region (dead until out_conv_mfma):
    ushort* xh = (ushort*)d_out;                     // 16,777,216 bf16 = 32 MiB
    ushort* xl = xh + (size_t)16777216;              // 32 MiB (ends at attn_out)

    // d_ws: av | weights | zero page (~17.7 MiB)
    ushort* av  = (ushort*)d_ws;                     // 8,388,608 bf16
    ushort* wvT = av + 8388608;                      // 294,912
    ushort* woT = wvT + 294912;                      // 294,912
    ushort* wqh = woT + 294912;                      // 147,456
    ushort* wql = wqh + 147456;                      // 147,456
    ushort* zp  = wql + 147456;                      // 512 (1 KB zero page)

    repack_w<<<2880, 256, 0, stream>>>(wq, wk, wv, wo, wvT, woT, wqh, wql, zp);
    repack_x2<<<B_ * VDIM, 256, 0, stream>>>(x, xh, xl);
    qkvattn2<<<B_ * 32, 256, 0, stream>>>(xh, xl, wvT, wqh, wql, zp, attn_out, av);
    out_conv_mfma<<<B_ * VDIM, 512, 0, stream>>>(x, av, woT, zp, sigma, out);
}

// Round 15
// 198.329 us; speedup vs baseline: 1.6245x; 1.1576x over previous
//
#include <hip/hip_runtime.h>
#include <hip/hip_bf16.h>

typedef __hip_bfloat16 bf16;
typedef float f32x4 __attribute__((ext_vector_type(4)));
typedef short s16x8 __attribute__((ext_vector_type(8)));

#define B_   16
#define CIN  256
#define CQK  32
#define CV   128
#define VDIM 64
#define TDIM 64
#define P    (VDIM * TDIM)   // 4096

static __device__ __forceinline__ ushort f2bf(float f) {
    bf16 h = __float2bfloat16(f);
    return *(ushort*)&h;
}
static __device__ __forceinline__ float bf2f(ushort u) {
    bf16 h = *(bf16*)&u;
    return __bfloat162float(h);
}

// async 16B-per-lane global -> LDS DMA (LDS dest = wave-uniform base + lane*16)
static __device__ __forceinline__ void gld16(const void* gsrc, void* ldst) {
    __builtin_amdgcn_global_load_lds(
        (const __attribute__((address_space(1))) void*)gsrc,
        (__attribute__((address_space(3))) void*)ldst,
        16, 0, 0);
}

#define MFMA16(A, B, C) __builtin_amdgcn_mfma_f32_16x16x32_bf16((A), (B), (C), 0, 0, 0)

// ---------------------------------------------------------------------------
// repack_w: weights -> [tap][oc][ci] bf16 (+ hi/lo split for q,k); zero zp page.
// ---------------------------------------------------------------------------
__global__ __launch_bounds__(256) void repack_w(
    const float* __restrict__ wq, const float* __restrict__ wk,
    const float* __restrict__ wv, const float* __restrict__ wo,
    ushort* __restrict__ wvT, ushort* __restrict__ woT,
    ushort* __restrict__ wqh, ushort* __restrict__ wql,
    ushort* __restrict__ zp)
{
    if (blockIdx.x == 0) ((uint*)zp)[threadIdx.x] = 0;   // 1KB zero page
    int i = blockIdx.x * 256 + threadIdx.x;
    const int NQK = 9 * 64 * 256;      // 147456
    const int NV  = 9 * 128 * 256;     // 294912
    if (i < NQK) {
        int tap = i / (64 * 256);
        int r   = i % (64 * 256);
        int oc  = r >> 8;
        int ci  = r & 255;
        const float* src = (oc < 32) ? wq : wk;
        float f = src[(size_t)(oc & 31) * 2304 + ci * 9 + tap];
        ushort h = f2bf(f);
        wqh[i] = h;
        wql[i] = f2bf(f - bf2f(h));
    } else if (i < NQK + NV) {
        i -= NQK;
        int tap = i / (128 * 256);
        int r   = i % (128 * 256);
        int oc  = r >> 8;
        int ci  = r & 255;
        wvT[i] = f2bf(wv[(size_t)oc * 2304 + ci * 9 + tap]);
    } else {
        i -= NQK + NV;
        int tap = i / (256 * 128);
        int r   = i % (256 * 128);
        int oc  = r >> 7;
        int ci  = r & 127;
        woT[i] = f2bf(wo[(size_t)oc * 1152 + ci * 9 + tap]);
    }
}

// ---------------------------------------------------------------------------
// repack_x2: x [B][256][64y][64t] f32 -> xh,xl [B][64t][64y][256ci] bf16
// ---------------------------------------------------------------------------
__global__ __launch_bounds__(256) void repack_x2(
    const float* __restrict__ x, ushort* __restrict__ xhd, ushort* __restrict__ xld)
{
    const int b = blockIdx.x >> 6;
    const int y = blockIdx.x & 63;
    __shared__ ushort th[64][257];
    __shared__ ushort tl_[64][257];
    const int t  = threadIdx.x & 63;
    const int cq = threadIdx.x >> 6;
    const float* xb = x + (((size_t)b * CIN) * VDIM + y) * TDIM;
    for (int ci = cq; ci < 256; ci += 4) {
        float f = xb[(size_t)ci * P + t];
        ushort h = f2bf(f);
        th[t][ci]  = h;
        tl_[t][ci] = f2bf(f - bf2f(h));
    }
    __syncthreads();
    const int ci4 = (threadIdx.x & 63) * 4;
    const int tr0 = threadIdx.x >> 6;
    for (int tr = tr0; tr < 64; tr += 4) {
        ushort4 uh, ul;
        uh.x = th[tr][ci4];     uh.y = th[tr][ci4 + 1];
        uh.z = th[tr][ci4 + 2]; uh.w = th[tr][ci4 + 3];
        ul.x = tl_[tr][ci4];     ul.y = tl_[tr][ci4 + 1];
        ul.z = tl_[tr][ci4 + 2]; ul.w = tl_[tr][ci4 + 3];
        const size_t o = ((((size_t)b * 64 + tr) * 64 + y) * 256 + ci4);
        *(ushort4*)(xhd + o) = uh;
        *(ushort4*)(xld + o) = ul;
    }
}

// ---------------------------------------------------------------------------
// Stage one [4 dx][66 yl][128 ci] tile (264 rows x 256B = 67.6KB) via gload_lds.
// dx spans t0-1 .. t0+2 (shared halo for the 2-column block). 66 DMA instrs
// split 17/17/16/16 across waves. Swizzle folded into source channel.
// ---------------------------------------------------------------------------
#define STAGE2(SRC, CI0)                                                          \
    {                                                                             \
        const int i0 = (w < 2) ? w * 17 : 34 + (w - 2) * 16;                      \
        const int nr = (w < 2) ? 17 : 16;                                         \
        for (int j = 0; j < nr; ++j) {                                            \
            const int ii  = i0 + j;                                               \
            const int row = ii * 4 + (lane >> 4);                                 \
            const int dxs = (row * 993) >> 16;                                    \
            const int yl  = row - dxs * 66;                                       \
            const int tp  = t0 + dxs - 1;                                         \
            const int yp  = yl - 1;                                               \
            const int chg = (lane & 15) ^ (row & 7);                              \
            const bool ok = ((unsigned)tp < 64u) && ((unsigned)yp < 64u);         \
            const ushort* sp = ok                                                 \
                ? (SRC) + ((((size_t)b * 64 + tp) * 64 + yp) * 256 + (CI0) + chg * 8) \
                : zp + (size_t)lane * 8;                                          \
            gld16(sp, btile + ii * 1024);                                         \
        }                                                                         \
    }

// Read the 4 B-fragments for dx-slice DXS (0..3) at k-step kk (swizzled read).
#define READ_BFR(BFR, DY, DXS, KK)                                                \
    {                                                                             \
        _Pragma("unroll")                                                         \
        for (int nf = 0; nf < 4; ++nf) {                                          \
            const int ylr = nf * 16 + (lane & 15) + (DY);                         \
            const int row = (DXS) * 66 + ylr;                                     \
            BFR[nf] = *(const s16x8*)(btile + row * 256 +                         \
                       ((((KK) * 64 + (lane >> 4) * 16)) ^ ((row & 7) << 4)));    \
        }                                                                         \
    }

// ---------------------------------------------------------------------------
// qkvattn2: fused q/k/v conv + MFMA attention, TWO t-columns per block.
// (R14 structure, unchanged — proven 118.8us)
// ---------------------------------------------------------------------------
__global__ __launch_bounds__(256) void qkvattn2(
    const ushort* __restrict__ xh, const ushort* __restrict__ xl,
    const ushort* __restrict__ wvT,
    const ushort* __restrict__ wqh, const ushort* __restrict__ wql,
    const ushort* __restrict__ zp,
    float* __restrict__ attn_out, ushort* __restrict__ av)
{
    // XCD-bijective swizzle (512 blocks, 8 XCDs, 64/XCD)
    const int bid  = ((blockIdx.x & 7) << 6) | (blockIdx.x >> 3);
    const int b    = bid >> 5;
    const int t0   = (bid & 31) * 2;
    const int tid  = threadIdx.x;
    const int lane = tid & 63;
    const int w    = tid >> 6;

    __shared__ __align__(16) char smem[67584];
    char* btile = smem;

    f32x4 accv[2][2][4];   // [col][m][nf]
    f32x4 accq[2][4];      // [col][nf]
#pragma unroll
    for (int c = 0; c < 2; ++c) {
#pragma unroll
        for (int m = 0; m < 2; ++m)
#pragma unroll
            for (int nf = 0; nf < 4; ++nf) accv[c][m][nf] = (f32x4){0.f, 0.f, 0.f, 0.f};
#pragma unroll
        for (int nf = 0; nf < 4; ++nf) accq[c][nf] = (f32x4){0.f, 0.f, 0.f, 0.f};
    }

    const int ocv  = w * 32 + (lane & 15);        // v channel base (m adds 16)
    const int ocqk = w * 16 + (lane & 15);        // combined q|k channel
    const int ko8  = (lane >> 4) * 8;

#define WVO(TAP, M, KK) (const s16x8*)(wvT + (size_t)((TAP) * 128 + ocv + (M) * 16) * 256 + ci0 + (KK) * 32 + ko8)
#define WQO(ARR, TAP, KK) (const s16x8*)((ARR) + (size_t)((TAP) * 64 + ocqk) * 256 + ci0 + (KK) * 32 + ko8)

    for (int chunk = 0; chunk < 2; ++chunk) {
        const int ci0 = chunk * 128;

        __syncthreads();              // protect btile from prior readers
        STAGE2(xh, ci0)
        __syncthreads();              // drains vmcnt -> DMAs complete

        // ---- merged v + qk-hi pass over x_hi: one weight batch, 2 columns ----
#pragma unroll 1
        for (int tap = 0; tap < 9; ++tap) {
            const int dy = tap / 3, dxp = tap % 3;
            s16x8 va[4], vb[4], ha[4], la[4];
#pragma unroll
            for (int kk = 0; kk < 4; ++kk) {
                va[kk] = *WVO(tap, 0, kk);
                vb[kk] = *WVO(tap, 1, kk);
                ha[kk] = *WQO(wqh, tap, kk);
                la[kk] = *WQO(wql, tap, kk);
            }
#pragma unroll
            for (int kk = 0; kk < 4; ++kk) {
                s16x8 bfr[4];
                READ_BFR(bfr, dy, dxp, kk)          // column 0
#pragma unroll
                for (int nf = 0; nf < 4; ++nf)
                    accv[0][0][nf] = MFMA16(va[kk], bfr[nf], accv[0][0][nf]);
#pragma unroll
                for (int nf = 0; nf < 4; ++nf)
                    accv[0][1][nf] = MFMA16(vb[kk], bfr[nf], accv[0][1][nf]);
#pragma unroll
                for (int nf = 0; nf < 4; ++nf)
                    accq[0][nf] = MFMA16(ha[kk], bfr[nf], accq[0][nf]);
#pragma unroll
                for (int nf = 0; nf < 4; ++nf)
                    accq[0][nf] = MFMA16(la[kk], bfr[nf], accq[0][nf]);

                s16x8 bfr1[4];
                READ_BFR(bfr1, dy, dxp + 1, kk)     // column 1 (same weights)
#pragma unroll
                for (int nf = 0; nf < 4; ++nf)
                    accv[1][0][nf] = MFMA16(va[kk], bfr1[nf], accv[1][0][nf]);
#pragma unroll
                for (int nf = 0; nf < 4; ++nf)
                    accv[1][1][nf] = MFMA16(vb[kk], bfr1[nf], accv[1][1][nf]);
#pragma unroll
                for (int nf = 0; nf < 4; ++nf)
                    accq[1][nf] = MFMA16(ha[kk], bfr1[nf], accq[1][nf]);
#pragma unroll
                for (int nf = 0; nf < 4; ++nf)
                    accq[1][nf] = MFMA16(la[kk], bfr1[nf], accq[1][nf]);
            }
        }

        __syncthreads();              // all reads of x_hi tile done
        STAGE2(xl, ci0)
        __syncthreads();

        // ---- qk lo pass (w_hi . x_lo), 2 columns per weight batch ----
#pragma unroll 1
        for (int tap = 0; tap < 9; ++tap) {
            const int dy = tap / 3, dxp = tap % 3;
            s16x8 ha[4];
#pragma unroll
            for (int kk = 0; kk < 4; ++kk) ha[kk] = *WQO(wqh, tap, kk);
#pragma unroll
            for (int kk = 0; kk < 4; ++kk) {
                s16x8 bfr[4];
                READ_BFR(bfr, dy, dxp, kk)
#pragma unroll
                for (int nf = 0; nf < 4; ++nf)
                    accq[0][nf] = MFMA16(ha[kk], bfr[nf], accq[0][nf]);
                s16x8 bfr1[4];
                READ_BFR(bfr1, dy, dxp + 1, kk)
#pragma unroll
                for (int nf = 0; nf < 4; ++nf)
                    accq[1][nf] = MFMA16(ha[kk], bfr1[nf], accq[1][nf]);
            }
        }
    }
#undef WVO
#undef WQO
    __syncthreads();   // btile dead; repurpose LDS for MFMA attention

    const int l15 = lane & 15, lg = lane >> 4;

    // ---- attention tail, per column (R12 compressed 32KB layout) ----
#pragma unroll
    for (int col = 0; col < 2; ++col) {
        // phase A: conv accumulators -> LDS (q@0 / k@8192 hi|lo, vsT@16384)
        {
            char* qkb = smem + ((w < 2) ? 0 : 8192);
            const int c0 = (w & 1) * 16 + lg * 4;
#pragma unroll
            for (int nf = 0; nf < 4; ++nf) {
                const int y = nf * 16 + l15;
                ushort4 h4, l4;
#pragma unroll
                for (int r = 0; r < 4; ++r) {
                    ushort h = f2bf(accq[col][nf][r]);
                    ((ushort*)&h4)[r] = h;
                    ((ushort*)&l4)[r] = f2bf(accq[col][nf][r] - bf2f(h));
                }
                const int swz = (y & 7) << 4;
                *(ushort4*)(qkb + y * 128 + ((2 * c0) ^ swz))      = h4;
                *(ushort4*)(qkb + y * 128 + ((64 + 2 * c0) ^ swz)) = l4;
            }
#pragma unroll
            for (int m = 0; m < 2; ++m)
#pragma unroll
                for (int nf = 0; nf < 4; ++nf) {
                    const int y = nf * 16 + l15;
#pragma unroll
                    for (int r = 0; r < 4; ++r) {
                        const int oc = w * 32 + m * 16 + lg * 4 + r;
                        *(ushort*)(smem + 16384 + oc * 128 + ((2 * y) ^ ((oc & 7) << 4)))
                            = f2bf(accv[col][m][nf][r]);
                    }
                }
        }
        __syncthreads();

        // phase B: S via MFMA (3-pass), softmax in-register; P overlays q/k
        f32x4 pv[4];
        {
            const int yq = w * 16 + l15;
            const int sq = (yq & 7) << 4;
            s16x8 qh = *(const s16x8*)(smem + yq * 128 + ((lg * 16) ^ sq));
            s16x8 ql = *(const s16x8*)(smem + yq * 128 + ((64 + lg * 16) ^ sq));
            s16x8 kh[4], kl[4];
#pragma unroll
            for (int jt = 0; jt < 4; ++jt) {
                const int jr = jt * 16 + l15;
                const int sk = (jr & 7) << 4;
                kh[jt] = *(const s16x8*)(smem + 8192 + jr * 128 + ((lg * 16) ^ sk));
                kl[jt] = *(const s16x8*)(smem + 8192 + jr * 128 + ((64 + lg * 16) ^ sk));
            }
            __syncthreads();   // ALL q/k reads complete -> safe to overlay P

            f32x4 sAcc[4];
#pragma unroll
            for (int jt = 0; jt < 4; ++jt) {
                f32x4 a = (f32x4){0.f, 0.f, 0.f, 0.f};
                a = MFMA16(qh, kh[jt], a);
                a = MFMA16(qh, kl[jt], a);
                a = MFMA16(ql, kh[jt], a);
                sAcc[jt] = a;
            }
            float mx[4], sum[4];
#pragma unroll
            for (int r = 0; r < 4; ++r)
                mx[r] = fmaxf(fmaxf(sAcc[0][r], sAcc[1][r]), fmaxf(sAcc[2][r], sAcc[3][r]));
#pragma unroll
            for (int d = 1; d < 16; d <<= 1)
#pragma unroll
                for (int r = 0; r < 4; ++r) mx[r] = fmaxf(mx[r], __shfl_xor(mx[r], d));
#pragma unroll
            for (int r = 0; r < 4; ++r) sum[r] = 0.f;
#pragma unroll
            for (int jt = 0; jt < 4; ++jt)
#pragma unroll
                for (int r = 0; r < 4; ++r) {
                    pv[jt][r] = expf(sAcc[jt][r] - mx[r]);
                    sum[r] += pv[jt][r];
                }
#pragma unroll
            for (int d = 1; d < 16; d <<= 1)
#pragma unroll
                for (int r = 0; r < 4; ++r) sum[r] += __shfl_xor(sum[r], d);
#pragma unroll
            for (int r = 0; r < 4; ++r) sum[r] = 1.f / sum[r];
#pragma unroll
            for (int jt = 0; jt < 4; ++jt)
#pragma unroll
                for (int r = 0; r < 4; ++r) pv[jt][r] *= sum[r];

            float* ao = attn_out + (size_t)(b * 64 + t0 + col) * 4096;
#pragma unroll
            for (int jt = 0; jt < 4; ++jt)
#pragma unroll
                for (int r = 0; r < 4; ++r)
                    ao[(w * 16 + lg * 4 + r) * 64 + jt * 16 + l15] = pv[jt][r];

#pragma unroll
            for (int jt = 0; jt < 4; ++jt)
#pragma unroll
                for (int r = 0; r < 4; ++r) {
                    const int i = w * 16 + lg * 4 + r;
                    const int j = jt * 16 + l15;
                    const int off = i * 128 + ((2 * j) ^ ((i & 7) << 4));
                    ushort h = f2bf(pv[jt][r]);
                    *(ushort*)(smem + off)        = h;
                    *(ushort*)(smem + 8192 + off) = f2bf(pv[jt][r] - bf2f(h));
                }
        }
        __syncthreads();

        // phase C: AV^T = V^T (Phi + Plo) via MFMA; avL overlays vsT
        {
            s16x8 vt[2][2];
#pragma unroll
            for (int c2 = 0; c2 < 2; ++c2)
#pragma unroll
                for (int ks = 0; ks < 2; ++ks) {
                    const int c = (w * 2 + c2) * 16 + l15;
                    vt[c2][ks] = *(const s16x8*)(smem + 16384 + c * 128 +
                                                 ((ks * 64 + lg * 16) ^ ((c & 7) << 4)));
                }
            __syncthreads();   // ALL vsT reads complete -> safe to overlay avL

            f32x4 acc2[2][4];
#pragma unroll
            for (int c2 = 0; c2 < 2; ++c2)
#pragma unroll
                for (int it = 0; it < 4; ++it) acc2[c2][it] = (f32x4){0.f, 0.f, 0.f, 0.f};

#pragma unroll
            for (int it = 0; it < 4; ++it) {
                const int i = it * 16 + l15;
                const int si = (i & 7) << 4;
                s16x8 ph[2], pl[2];
#pragma unroll
                for (int ks = 0; ks < 2; ++ks) {
                    ph[ks] = *(const s16x8*)(smem + i * 128 + ((ks * 64 + lg * 16) ^ si));
                    pl[ks] = *(const s16x8*)(smem + 8192 + i * 128 + ((ks * 64 + lg * 16) ^ si));
                }
#pragma unroll
                for (int c2 = 0; c2 < 2; ++c2)
#pragma unroll
                    for (int ks = 0; ks < 2; ++ks) {
                        acc2[c2][it] = MFMA16(vt[c2][ks], ph[ks], acc2[c2][it]);
                        acc2[c2][it] = MFMA16(vt[c2][ks], pl[ks], acc2[c2][it]);
                    }
            }
#pragma unroll
            for (int c2 = 0; c2 < 2; ++c2)
#pragma unroll
                for (int it = 0; it < 4; ++it)
#pragma unroll
                    for (int r = 0; r < 4; ++r) {
                        const int c = (w * 2 + c2) * 16 + lg * 4 + r;
                        const int i = it * 16 + l15;
                        *(ushort*)(smem + 16384 + i * 256 + ((2 * c) ^ ((i & 7) << 4)))
                            = f2bf(acc2[c2][it][r]);
                    }
        }
        __syncthreads();

        // phase D: avL -> global, fully coalesced
        {
            uint* avg = (uint*)(av + (size_t)(b * 64 + t0 + col) * 8192);
#pragma unroll
            for (int t = 0; t < 16; ++t) {
                const int idx = t * 256 + tid;
                const int i  = idx >> 6;
                const int cc = idx & 63;
                avg[idx] = *(const uint*)(smem + 16384 + i * 256 + ((4 * cc) ^ ((i & 7) << 4)));
            }
        }
        __syncthreads();   // protects next column's phase A overlay
    }
}

// ---------------------------------------------------------------------------
// out_conv_mfma2: 512-thread / 8-wave block = (b, y-pair): M=256 oc,
// N=2x64 t, K=128ci*9tap. Stage ONE [4 dy][66 tl][128 ci] av tile (66KB,
// shared halo); each wave's weight batch feeds col0+col1 (y0,y0+1) -> weight
// L2 traffic halved (R14's proven lever applied to out_conv).
// Per-column MFMA order identical to R11 -> bitwise-identical output.
// ---------------------------------------------------------------------------
__global__ __launch_bounds__(512) void out_conv_mfma2(
    const float* __restrict__ x,
    const ushort* __restrict__ av,
    const ushort* __restrict__ woT,
    const ushort* __restrict__ zp,
    const float* __restrict__ sigma,
    float* __restrict__ out)
{
    // XCD-bijective swizzle (512 blocks, 64/XCD)
    const int bid  = ((blockIdx.x & 7) << 6) | (blockIdx.x >> 3);
    const int y0   = (bid & 31) * 2;
    const int b    = bid >> 5;
    const int tid  = threadIdx.x;
    const int lane = tid & 63;
    const int w    = tid >> 6;           // 0..7

    __shared__ __align__(16) char smem[67584];
    char* btile = smem;

    f32x4 acc[2][2][4];   // [col][m][nf]
#pragma unroll
    for (int c = 0; c < 2; ++c)
#pragma unroll
        for (int m = 0; m < 2; ++m)
#pragma unroll
            for (int nf = 0; nf < 4; ++nf) acc[c][m][nf] = (f32x4){0.f, 0.f, 0.f, 0.f};

    // stage [4 dy][66 tl][128 ci] from av (dy spans y0-1..y0+2); 66 DMA rows
    // split 9/9/8/8/8/8/8/8 across 8 waves. Swizzle folded into source.
    {
        const int i0 = (w < 2) ? w * 9 : 18 + (w - 2) * 8;
        const int ni = (w < 2) ? 9 : 8;
        for (int j = 0; j < ni; ++j) {
            const int ii  = i0 + j;
            const int row = ii * 4 + (lane >> 4);
            const int dys = (row * 993) >> 16;
            const int tl  = row - dys * 66;
            const int yp  = y0 + dys - 1;
            const int tp  = tl - 1;
            const int chg = (lane & 15) ^ (row & 7);
            const bool ok = ((unsigned)yp < 64u) && ((unsigned)tp < 64u);
            const ushort* sp = ok
                ? av + ((((size_t)b * 64 + tp) * 64 + yp) * 128 + chg * 8)
                : zp + (size_t)lane * 8;
            gld16(sp, btile + ii * 1024);
        }
    }
    __syncthreads();

    const int oc  = w * 32 + (lane & 15);
    const int ko8 = (lane >> 4) * 8;
#define WOO(TAP, M, KK) (const s16x8*)(woT + (size_t)((TAP) * 256 + oc + (M) * 16) * 128 + (KK) * 32 + ko8)
#pragma unroll 1
    for (int tap = 0; tap < 9; ++tap) {
        const int dy = tap / 3, dxp = tap % 3;
        s16x8 wa[4], wb[4];
#pragma unroll
        for (int kk = 0; kk < 4; ++kk) {
            wa[kk] = *WOO(tap, 0, kk);
            wb[kk] = *WOO(tap, 1, kk);
        }
#pragma unroll
        for (int kk = 0; kk < 4; ++kk) {
#pragma unroll
            for (int col = 0; col < 2; ++col) {
                s16x8 bfr[4];
#pragma unroll
                for (int nf = 0; nf < 4; ++nf) {
                    const int tl = nf * 16 + (lane & 15) + dxp;
                    const int row = (dy + col) * 66 + tl;
                    const int bir = kk * 64 + (lane >> 4) * 16;
                    bfr[nf] = *(const s16x8*)(btile + row * 256 + (bir ^ ((row & 7) << 4)));
                }
#pragma unroll
                for (int nf = 0; nf < 4; ++nf)
                    acc[col][0][nf] = MFMA16(wa[kk], bfr[nf], acc[col][0][nf]);
#pragma unroll
                for (int nf = 0; nf < 4; ++nf)
                    acc[col][1][nf] = MFMA16(wb[kk], bfr[nf], acc[col][1][nf]);
            }
        }
    }
#undef WOO

    const float s = sigma[0];
#pragma unroll
    for (int col = 0; col < 2; ++col)
#pragma unroll
        for (int m = 0; m < 2; ++m)
#pragma unroll
            for (int nf = 0; nf < 4; ++nf)
#pragma unroll
                for (int r = 0; r < 4; ++r) {
                    const int occ = w * 32 + m * 16 + (lane >> 4) * 4 + r;
                    const int t   = nf * 16 + (lane & 15);
                    const size_t a = (((size_t)b * 256 + occ) * 64 + (y0 + col)) * 64 + t;
                    out[a] = x[a] + s * acc[col][m][nf][r];
                }
}

// ---------------------------------------------------------------------------
extern "C" void kernel_launch(void* const* d_in, const int* in_sizes, int n_in,
                              void* d_out, int out_size, void* d_ws, size_t ws_size,
                              hipStream_t stream)
{
    const float* x     = (const float*)d_in[0];
    const float* wq    = (const float*)d_in[1];
    const float* wk    = (const float*)d_in[2];
    const float* wv    = (const float*)d_in[3];
    const float* wo    = (const float*)d_in[4];
    const float* sigma = (const float*)d_in[5];

    float* out      = (float*)d_out;                 // [16,256,64,64]
    float* attn_out = out + (size_t)16777216;        // [1024,64,64]

    // x hi/lo bf16 alias the out-image region (dead until out_conv_mfma2):
    ushort* xh = (ushort*)d_out;                     // 16,777,216 bf16 = 32 MiB
    ushort* xl = xh + (size_t)16777216;              // 32 MiB (ends at attn_out)

    // d_ws: av | weights | zero page (~17.7 MiB)
    ushort* av  = (ushort*)d_ws;                     // 8,388,608 bf16
    ushort* wvT = av + 8388608;                      // 294,912
    ushort* woT = wvT + 294912;                      // 294,912
    ushort* wqh = woT + 294912;                      // 147,456
    ushort* wql = wqh + 147456;                      // 147,456
    ushort* zp  = wql + 147456;                      // 512 (1 KB zero page)

    repack_w<<<2880, 256, 0, stream>>>(wq, wk, wv, wo, wvT, woT, wqh, wql, zp);
    repack_x2<<<B_ * VDIM, 256, 0, stream>>>(x, xh, xl);
    qkvattn2<<<B_ * 32, 256, 0, stream>>>(xh, xl, wvT, wqh, wql, zp, attn_out, av);
    out_conv_mfma2<<<B_ * 32, 512, 0, stream>>>(x, av, woT, zp, sigma, out);
}